// Round 9
// baseline (10281.256 us; speedup 1.0000x reference)
//
#include <hip/hip_runtime.h>
#include <hip/hip_bf16.h>

// ---------------------------------------------------------------------------
// VQ-VAE forward — R9: GREEN CANDIDATE (R8 probe offset removed).
// Key facts (proven R0-R8):
//  * output = f32: [z_d (12,582,912), loss (1)]; loss at out[out_size-1]
//  * np reference: VQ argmin computed in f32 via (sz+scc)-2*dot — must mimic
//    (f64 argmin differs at ~14 near-tie positions -> 1.64 absmax blotches)
//  * loss: f64 accumulation matches np to <1e-6
// Pipeline: f64 encoder (conv1 recompute 2-pass BN1 stats; fused conv1+BN1+
// ReLU -> conv2 tile; conv3), f32-mimic VQ argmin + f64 loss, f32 decoder.
// ---------------------------------------------------------------------------

#define EPS 1e-5

__global__ void zero_stats_k(double* s, int n) {
    int i = blockIdx.x * blockDim.x + threadIdx.x;
    if (i < n) s[i] = 0.0;
}

__device__ __forceinline__ void block_reduce_add(double v, double* target) {
#pragma unroll
    for (int o = 32; o; o >>= 1) v += __shfl_down(v, o);
    __shared__ double ls[4];
    int wid = threadIdx.x >> 6, lane = threadIdx.x & 63;
    if (lane == 0) ls[wid] = v;
    __syncthreads();
    if (threadIdx.x == 0) {
        double a = ls[0] + ls[1] + ls[2] + ls[3];
        atomicAdd(target, a);
    }
    __syncthreads();
}

__device__ __forceinline__ double conv1_val(const float* __restrict__ x,
                                            const float* __restrict__ w,
                                            const float* __restrict__ bias,
                                            int n, int co, int oy, int ox) {
    double acc = (double)bias[co];
    const float* wp = w + co * 48;
    const float* xp = x + (size_t)n * 3 * 65536;
    int iy0 = oy * 2 - 1, ix0 = ox * 2 - 1;
    for (int ci = 0; ci < 3; ++ci) {
        const float* xc = xp + (size_t)ci * 65536;
        const float* wc = wp + ci * 16;
#pragma unroll
        for (int ky = 0; ky < 4; ++ky) {
            int iy = iy0 + ky;
            if ((unsigned)iy >= 256u) continue;
#pragma unroll
            for (int kx = 0; kx < 4; ++kx) {
                int ix = ix0 + kx;
                if ((unsigned)ix >= 256u) continue;
                acc = fma((double)xc[iy * 256 + ix], (double)wc[ky * 4 + kx], acc);
            }
        }
    }
    return acc;
}

template <int MODE>
__global__ void conv1_stat_k(const float* __restrict__ x, const float* __restrict__ w,
                             const float* __restrict__ bias, double* __restrict__ stats) {
    int hw = blockIdx.x * 256 + threadIdx.x;
    int co = blockIdx.y, n = blockIdx.z;
    double v = conv1_val(x, w, bias, n, co, hw >> 7, hw & 127);
    if (MODE == 0) {
        block_reduce_add(v, &stats[co]);
    } else {
        double m = stats[co] * (1.0 / 1048576.0);
        double d = v - m;
        block_reduce_add(d * d, &stats[64 + co]);
    }
}

__global__ void fused_conv2_k(const float* __restrict__ x, const float* __restrict__ eW1,
                              const float* __restrict__ eb1, const float* __restrict__ eg1,
                              const float* __restrict__ ebt1, const float* __restrict__ eW2,
                              const float* __restrict__ eb2, const double* __restrict__ stats1,
                              double* __restrict__ h2) {
    int tile = blockIdx.x, n = blockIdx.y;
    int oy0 = (tile >> 3) << 3, ox0 = (tile & 7) << 3;
    __shared__ double h1t[16][18][18];
    int tid = threadIdx.x;
    int hy0 = oy0 * 2 - 1, hx0 = ox0 * 2 - 1;
    for (int idx = tid; idx < 16 * 18 * 18; idx += 256) {
        int ci = idx / 324, rem = idx - ci * 324, r = rem / 18, c = rem - r * 18;
        int hy = hy0 + r, hx = hx0 + c;
        double val = 0.0;
        if ((unsigned)hy < 128u && (unsigned)hx < 128u) {
            double acc = conv1_val(x, eW1, eb1, n, ci, hy, hx);
            double m = stats1[ci] * (1.0 / 1048576.0);
            double v = stats1[64 + ci] * (1.0 / 1048576.0);
            double sc = (double)eg1[ci] / sqrt(v + EPS);
            double sh = (double)ebt1[ci] - m * sc;
            val = fma(acc, sc, sh);
            val = val > 0.0 ? val : 0.0;
        }
        h1t[ci][r][c] = val;
    }
    __syncthreads();
    int s = tid & 63, ly = s >> 3, lx = s & 7;
    int oy = oy0 + ly, ox = ox0 + lx;
    int co0 = (tid >> 6) * 8;
    for (int co = co0; co < co0 + 8; ++co) {
        double acc = (double)eb2[co];
        const float* wp = eW2 + co * 256;
        for (int ci = 0; ci < 16; ++ci) {
            const float* wc = wp + ci * 16;
#pragma unroll
            for (int ky = 0; ky < 4; ++ky)
#pragma unroll
                for (int kx = 0; kx < 4; ++kx)
                    acc = fma(h1t[ci][ly * 2 + ky][lx * 2 + kx],
                              (double)wc[ky * 4 + kx], acc);
        }
        h2[((size_t)(n * 32 + co) << 12) + (oy << 6) + ox] = acc;
    }
}

template <typename Tin, typename Tout>
__global__ void conv_k4s2(const Tin* __restrict__ x, const float* __restrict__ w,
                          const float* __restrict__ bias, Tout* __restrict__ y,
                          int Ci, int Hi, int Wi, int Ho, int Wo) {
    int hw = blockIdx.x * blockDim.x + threadIdx.x;
    int co = blockIdx.y, n = blockIdx.z, Co = gridDim.y;
    int oy = hw / Wo, ox = hw - oy * Wo;
    double acc = (double)bias[co];
    const float* wp = w + co * Ci * 16;
    const Tin* xp = x + (size_t)(n * Ci) * Hi * Wi;
    int iy0 = oy * 2 - 1, ix0 = ox * 2 - 1;
    for (int ci = 0; ci < Ci; ++ci) {
        const Tin* xc = xp + (size_t)ci * Hi * Wi;
        const float* wc = wp + ci * 16;
#pragma unroll
        for (int ky = 0; ky < 4; ++ky) {
            int iy = iy0 + ky;
            if ((unsigned)iy >= (unsigned)Hi) continue;
#pragma unroll
            for (int kx = 0; kx < 4; ++kx) {
                int ix = ix0 + kx;
                if ((unsigned)ix >= (unsigned)Wi) continue;
                acc = fma((double)xc[iy * Wi + ix], (double)wc[ky * 4 + kx], acc);
            }
        }
    }
    y[(size_t)(n * Co + co) * Ho * Wo + hw] = (Tout)acc;
}

__global__ void deconv_k4s2(const float* __restrict__ x, const float* __restrict__ w,
                            const float* __restrict__ bias, float* __restrict__ y,
                            int Ci, int Hi, int Wi) {
    int Ho = Hi * 2, Wo = Wi * 2;
    int hw = blockIdx.x * blockDim.x + threadIdx.x;
    int co = blockIdx.y, n = blockIdx.z, Co = gridDim.y;
    int oy = hw / Wo, ox = hw - oy * Wo;
    int qy = oy >> 1, ry = oy & 1;
    int qx = ox >> 1, rx = ox & 1;
    int kyA = ry ? 1 : 0, iyA = ry ? qy : qy - 1;
    int kyB = ry ? 3 : 2, iyB = ry ? qy + 1 : qy;
    int kxA = rx ? 1 : 0, ixA = rx ? qx : qx - 1;
    int kxB = rx ? 3 : 2, ixB = rx ? qx + 1 : qx;
    bool vyA = (unsigned)iyA < (unsigned)Hi, vyB = (unsigned)iyB < (unsigned)Hi;
    bool vxA = (unsigned)ixA < (unsigned)Wi, vxB = (unsigned)ixB < (unsigned)Wi;
    double acc = (double)bias[co];
    const float* wp = w + co * Ci * 16;
    const float* xp = x + (size_t)(n * Ci) * Hi * Wi;
    for (int ci = 0; ci < Ci; ++ci) {
        const float* xc = xp + (size_t)ci * Hi * Wi;
        const float* wc = wp + ci * 16;
        if (vyA) {
            if (vxA) acc = fma((double)xc[iyA * Wi + ixA], (double)wc[kyA * 4 + kxA], acc);
            if (vxB) acc = fma((double)xc[iyA * Wi + ixB], (double)wc[kyA * 4 + kxB], acc);
        }
        if (vyB) {
            if (vxA) acc = fma((double)xc[iyB * Wi + ixA], (double)wc[kyB * 4 + kxA], acc);
            if (vxB) acc = fma((double)xc[iyB * Wi + ixB], (double)wc[kyB * 4 + kxB], acc);
        }
    }
    y[(size_t)(n * Co + co) * Ho * Wo + hw] = (float)acc;
}

template <typename T, int MODE>
__global__ void bn_stat_k(const T* __restrict__ y, double* __restrict__ stats,
                          int C, int HW, double invCnt) {
    int c = blockIdx.x, n = blockIdx.y;
    const T* p = y + (size_t)(n * C + c) * HW;
    double m = (MODE == 1) ? stats[c] * invCnt : 0.0;
    double s = 0.0;
    for (int i = threadIdx.x; i < HW; i += blockDim.x) {
        double v = (double)p[i];
        if (MODE == 0) s += v;
        else { double d = v - m; s = fma(d, d, s); }
    }
    block_reduce_add(s, MODE == 0 ? &stats[c] : &stats[64 + c]);
}

template <typename T>
__global__ void bn_relu_k(T* __restrict__ y, const double* __restrict__ stats,
                          const float* __restrict__ g, const float* __restrict__ b,
                          int HW, double invCnt) {
    int hw = blockIdx.x * blockDim.x + threadIdx.x;
    int c = blockIdx.y, n = blockIdx.z, C = gridDim.y;
    double m = stats[c] * invCnt;
    double v = stats[64 + c] * invCnt;
    double sc = (double)g[c] / sqrt(v + EPS);
    double sh = (double)b[c] - m * sc;
    size_t i = (size_t)(n * C + c) * HW + hw;
    double val = fma((double)y[i], sc, sh);
    y[i] = (T)(val > 0.0 ? val : 0.0);
}

__global__ void bn_tanh_out_k(const float* __restrict__ y, const double* __restrict__ stats,
                              const float* __restrict__ g, const float* __restrict__ b,
                              float* __restrict__ out, int HW, double invCnt) {
    int hw = blockIdx.x * blockDim.x + threadIdx.x;
    int c = blockIdx.y, n = blockIdx.z, C = gridDim.y;
    double m = stats[c] * invCnt;
    double v = stats[64 + c] * invCnt;
    double sc = (double)g[c] / sqrt(v + EPS);
    double sh = (double)b[c] - m * sc;
    size_t i = (size_t)(n * C + c) * HW + hw;
    double val = fma((double)y[i], sc, sh);
    out[i] = (float)tanh(val);
}

// numpy-style 8-accumulator f32 sum of 64 elements
__device__ __forceinline__ float np_sum64(const float* a) {
    float r[8];
#pragma unroll
    for (int j = 0; j < 8; ++j) r[j] = a[j];
#pragma unroll
    for (int m = 1; m < 8; ++m)
#pragma unroll
        for (int j = 0; j < 8; ++j) r[j] += a[m * 8 + j];
    return ((r[0] + r[1]) + (r[2] + r[3])) + ((r[4] + r[5]) + (r[6] + r[7]));
}

// VQ: np-mimic f32 argmin selects quant; exact f64 best-dist feeds the loss.
__global__ void vq_k(const double* __restrict__ ze, const float* __restrict__ cb,
                     float* __restrict__ quant, double* __restrict__ lossAcc) {
    int p = blockIdx.x * blockDim.x + threadIdx.x;
    int n = p >> 10, hw = p & 1023;
    const double* zp = ze + (size_t)n * 65536 + hw;
    double z[64];
    float z32[64], zz[64];
#pragma unroll
    for (int d = 0; d < 64; ++d) {
        z[d] = zp[d * 1024];
        z32[d] = (float)z[d];
        zz[d] = z32[d] * z32[d];
    }
    float sz = np_sum64(zz);

    double best = 1e300;
    float bestf = 3.4e38f;
    int bif = 0;
    for (int k = 0; k < 512; ++k) {
        const float* c = cb + (k << 6);
        double dist = 0.0;
        float cc[64];
        float dot = 0.f;
#pragma unroll
        for (int d = 0; d < 64; ++d) {
            float cd = c[d];
            double diff = z[d] - (double)cd;
            dist = fma(diff, diff, dist);
            cc[d] = cd * cd;
            dot = fmaf(z32[d], cd, dot);
        }
        float scc = np_sum64(cc);
        float distf = (sz + scc) - 2.f * dot;
        if (dist < best) best = dist;
        if (distf < bestf) { bestf = distf; bif = k; }
    }
    const float* c = cb + (bif << 6);
    float* qp = quant + (size_t)n * 65536 + hw;
#pragma unroll
    for (int d = 0; d < 64; ++d) qp[d * 1024] = c[d];
    double s = best;
#pragma unroll
    for (int o = 32; o; o >>= 1) s += __shfl_down(s, o);
    if ((threadIdx.x & 63) == 0) atomicAdd(lossAcc, s);
}

__global__ void finalize_loss_k(const double* lossAcc, float* out, int idx) {
    if (threadIdx.x == 0 && blockIdx.x == 0)
        out[idx] = (float)(2.0 * (*lossAcc) / 4194304.0);
}

extern "C" void kernel_launch(void* const* d_in, const int* in_sizes, int n_in,
                              void* d_out, int out_size, void* d_ws, size_t ws_size,
                              hipStream_t stream) {
    const float* x   = (const float*)d_in[0];
    const float* cb  = (const float*)d_in[1];
    const float* eW1 = (const float*)d_in[2];
    const float* eb1 = (const float*)d_in[3];
    const float* eg1 = (const float*)d_in[4];
    const float* ebt1= (const float*)d_in[5];
    const float* eW2 = (const float*)d_in[6];
    const float* eb2 = (const float*)d_in[7];
    const float* eg2 = (const float*)d_in[8];
    const float* ebt2= (const float*)d_in[9];
    const float* eW3 = (const float*)d_in[10];
    const float* eb3 = (const float*)d_in[11];
    const float* eg3 = (const float*)d_in[12];
    const float* ebt3= (const float*)d_in[13];
    const float* dW1 = (const float*)d_in[14];
    const float* db1 = (const float*)d_in[15];
    const float* dg1 = (const float*)d_in[16];
    const float* dbt1= (const float*)d_in[17];
    const float* dW2 = (const float*)d_in[18];
    const float* db2 = (const float*)d_in[19];
    const float* dg2 = (const float*)d_in[20];
    const float* dbt2= (const float*)d_in[21];
    const float* dW3 = (const float*)d_in[22];
    const float* db3 = (const float*)d_in[23];
    const float* dg3 = (const float*)d_in[24];
    const float* dbt3= (const float*)d_in[25];

    float* out = (float*)d_out;
    char* ws = (char*)d_ws;
    double* h2   = (double*)ws;
    double* z    = (double*)(ws + 67108864);
    float* quant = (float*)ws;
    float* d1    = (float*)(ws + 16777216);
    float* d2    = (float*)(ws + 50331648);
    float* d3    = (float*)ws;
    double* stats = (double*)(ws + 117440512);
    double* lossAcc = stats + 768;
    dim3 B(256);

    zero_stats_k<<<4, B, 0, stream>>>(stats, 776);

    conv1_stat_k<0><<<dim3(64, 16, 64), B, 0, stream>>>(x, eW1, eb1, stats + 0);
    conv1_stat_k<1><<<dim3(64, 16, 64), B, 0, stream>>>(x, eW1, eb1, stats + 0);
    fused_conv2_k<<<dim3(64, 64), B, 0, stream>>>(x, eW1, eb1, eg1, ebt1, eW2, eb2,
                                                  stats + 0, h2);
    bn_stat_k<double, 0><<<dim3(32, 64), B, 0, stream>>>(h2, stats + 128, 32, 4096, 1.0 / 262144.0);
    bn_stat_k<double, 1><<<dim3(32, 64), B, 0, stream>>>(h2, stats + 128, 32, 4096, 1.0 / 262144.0);
    bn_relu_k<double><<<dim3(16, 32, 64), B, 0, stream>>>(h2, stats + 128, eg2, ebt2,
                                                          4096, 1.0 / 262144.0);
    conv_k4s2<double, double><<<dim3(4, 64, 64), B, 0, stream>>>(h2, eW3, eb3, z,
                                                                 32, 64, 64, 32, 32);
    bn_stat_k<double, 0><<<dim3(64, 64), B, 0, stream>>>(z, stats + 256, 64, 1024, 1.0 / 65536.0);
    bn_stat_k<double, 1><<<dim3(64, 64), B, 0, stream>>>(z, stats + 256, 64, 1024, 1.0 / 65536.0);
    bn_relu_k<double><<<dim3(4, 64, 64), B, 0, stream>>>(z, stats + 256, eg3, ebt3,
                                                         1024, 1.0 / 65536.0);
    vq_k<<<256, B, 0, stream>>>(z, cb, quant, lossAcc);
    finalize_loss_k<<<1, 64, 0, stream>>>(lossAcc, out, out_size - 1);

    deconv_k4s2<<<dim3(16, 32, 64), B, 0, stream>>>(quant, dW1, db1, d1, 64, 32, 32);
    bn_stat_k<float, 0><<<dim3(32, 64), B, 0, stream>>>(d1, stats + 384, 32, 4096, 1.0 / 262144.0);
    bn_stat_k<float, 1><<<dim3(32, 64), B, 0, stream>>>(d1, stats + 384, 32, 4096, 1.0 / 262144.0);
    bn_relu_k<float><<<dim3(16, 32, 64), B, 0, stream>>>(d1, stats + 384, dg1, dbt1,
                                                         4096, 1.0 / 262144.0);
    deconv_k4s2<<<dim3(64, 16, 64), B, 0, stream>>>(d1, dW2, db2, d2, 32, 64, 64);
    bn_stat_k<float, 0><<<dim3(16, 64), B, 0, stream>>>(d2, stats + 512, 16, 16384, 1.0 / 1048576.0);
    bn_stat_k<float, 1><<<dim3(16, 64), B, 0, stream>>>(d2, stats + 512, 16, 16384, 1.0 / 1048576.0);
    bn_relu_k<float><<<dim3(64, 16, 64), B, 0, stream>>>(d2, stats + 512, dg2, dbt2,
                                                         16384, 1.0 / 1048576.0);
    deconv_k4s2<<<dim3(256, 3, 64), B, 0, stream>>>(d2, dW3, db3, d3, 16, 128, 128);
    bn_stat_k<float, 0><<<dim3(3, 64), B, 0, stream>>>(d3, stats + 640, 3, 65536, 1.0 / 4194304.0);
    bn_stat_k<float, 1><<<dim3(3, 64), B, 0, stream>>>(d3, stats + 640, 3, 65536, 1.0 / 4194304.0);
    bn_tanh_out_k<<<dim3(256, 3, 64), B, 0, stream>>>(d3, stats + 640, dg3, dbt3, out,
                                                      65536, 1.0 / 4194304.0);
}

// Round 10
// 2523.148 us; speedup vs baseline: 4.0748x; 4.0748x over previous
//
#include <hip/hip_runtime.h>
#include <hip/hip_bf16.h>

// ---------------------------------------------------------------------------
// VQ-VAE forward — R10: memory-locality rewrite (R9 passed @ 10.28ms).
//  * All convs/deconvs LDS-stage inputs (fixes 91x HBM over-fetch).
//  * f32 activation storage everywhere; f64 accumulation in encoder
//    (z perturbation ~1e-7 -> ~0.03 expected argmin flips: safe).
//  * VQ: bit-identical np-mimic f32 argmin (np_sum64 / seq-FMA dot /
//    (sz+scc)-2dot, scc hoisted = same op order); exact f64 dist of the
//    SELECTED code feeds the loss.
//  * Single-pass f64 BN stats (E[x^2]-m^2; proven equivalent R4).
// ws layout (bytes):
//   h2  f32 [64,32,64,64]   [0,          33,554,432)
//   z   f32 [64,64,32,32]   [33,554,432, 50,331,648)
//   quant f32               [50,331,648, 67,108,864)
//   d1  f32 [64,32,64,64]   [67,108,864, 100,663,296)
//   d2  f32 [64,16,128,128] [0,          67,108,864)   (h2,z,quant dead)
//   d3  f32 [64,3,256,256]  [67,108,864, 117,440,512)  (d1 dead)
//   stats f64[327]          @117,440,512   (tight-packed per layer)
//   scc  f32[512]           @117,443,200
// stats offsets (doubles): c1@0(16+16) bn2@32(32+32) bn3@96(64+64)
//   bn4@224(32+32) bn5@288(16+16) bn6@320(3+3) loss@326
// ---------------------------------------------------------------------------

#define EPS 1e-5

__global__ void zero_stats_k(double* s, int n) {
    int i = blockIdx.x * blockDim.x + threadIdx.x;
    if (i < n) s[i] = 0.0;
}

// reduce two f64 values across 256 threads, atomicAdd into t1,t2
__device__ __forceinline__ void block_reduce2(double v1, double v2,
                                              double* t1, double* t2) {
#pragma unroll
    for (int o = 32; o; o >>= 1) {
        v1 += __shfl_down(v1, o);
        v2 += __shfl_down(v2, o);
    }
    __shared__ double ls[4][2];
    int wid = threadIdx.x >> 6, lane = threadIdx.x & 63;
    if (lane == 0) { ls[wid][0] = v1; ls[wid][1] = v2; }
    __syncthreads();
    if (threadIdx.x == 0) {
        double a = ls[0][0] + ls[1][0] + ls[2][0] + ls[3][0];
        double b = ls[0][1] + ls[1][1] + ls[2][1] + ls[3][1];
        atomicAdd(t1, a);
        atomicAdd(t2, b);
    }
    __syncthreads();
}

// ---- conv1 stats, single pass, LDS-staged x. grid(64,64) ----
__global__ void conv1_stats_k(const float* __restrict__ x, const float* __restrict__ w,
                              const float* __restrict__ bias, double* __restrict__ stats) {
    __shared__ float xs[3][6][258];
    int c = blockIdx.x, n = blockIdx.y, tid = threadIdx.x;
    int iyBase = 4 * c - 1;
    for (int idx = tid; idx < 3 * 6 * 258; idx += 256) {
        int ch = idx / 1548, rem = idx - ch * 1548, r = rem / 258, cc = rem - r * 258;
        int iy = iyBase + r, ix = cc - 1;
        float v = 0.f;
        if ((unsigned)iy < 256u && (unsigned)ix < 256u)
            v = x[(size_t)(n * 3 + ch) * 65536 + iy * 256 + ix];
        xs[ch][r][cc] = v;
    }
    __syncthreads();
    int oy = 2 * c + (tid >> 7), ox = tid & 127;
    int lr = 2 * (tid >> 7);                 // LDS row of iy0 = 2*oy-1
    int lc = 2 * ox;                         // LDS col of ix0 = 2*ox-1 (+1 pad)
    for (int co = 0; co < 16; ++co) {
        double acc = (double)bias[co];
        const float* wp = w + co * 48;
#pragma unroll
        for (int ci = 0; ci < 3; ++ci)
#pragma unroll
            for (int ky = 0; ky < 4; ++ky)
#pragma unroll
                for (int kx = 0; kx < 4; ++kx)
                    acc = fma((double)xs[ci][lr + ky][lc + kx],
                              (double)wp[ci * 16 + ky * 4 + kx], acc);
        block_reduce2(acc, acc * acc, &stats[co], &stats[16 + co]);
    }
    (void)oy;
}

// ---- fused conv1+BN1+ReLU -> conv2 -> h2 f32. grid(64 tiles,64 n) ----
__global__ void fused_conv2_k(const float* __restrict__ x, const float* __restrict__ eW1,
                              const float* __restrict__ eb1, const float* __restrict__ eg1,
                              const float* __restrict__ ebt1, const float* __restrict__ eW2,
                              const float* __restrict__ eb2, const double* __restrict__ stats,
                              float* __restrict__ h2) {
    __shared__ float xs[3][38][38];
    __shared__ float h1s[16][18][18];
    int tile = blockIdx.x, n = blockIdx.y, tid = threadIdx.x;
    int ty = tile >> 3, tx = tile & 7;
    int oy0 = 8 * ty, ox0 = 8 * tx;
    int iyBase = 32 * ty - 3, ixBase = 32 * tx - 3;
    for (int idx = tid; idx < 3 * 38 * 38; idx += 256) {
        int ch = idx / 1444, rem = idx - ch * 1444, r = rem / 38, cc = rem - r * 38;
        int iy = iyBase + r, ix = ixBase + cc;
        float v = 0.f;
        if ((unsigned)iy < 256u && (unsigned)ix < 256u)
            v = x[(size_t)(n * 3 + ch) * 65536 + iy * 256 + ix];
        xs[ch][r][cc] = v;
    }
    __syncthreads();
    int hy0 = 16 * ty - 1, hx0 = 16 * tx - 1;
    for (int idx = tid; idx < 16 * 18 * 18; idx += 256) {
        int ci = idx / 324, rem = idx - ci * 324, r = rem / 18, cc = rem - r * 18;
        int hy = hy0 + r, hx = hx0 + cc;
        float val = 0.f;
        if ((unsigned)hy < 128u && (unsigned)hx < 128u) {
            double acc = (double)eb1[ci];
            const float* wp = eW1 + ci * 48;
#pragma unroll
            for (int c3 = 0; c3 < 3; ++c3)
#pragma unroll
                for (int ky = 0; ky < 4; ++ky)
#pragma unroll
                    for (int kx = 0; kx < 4; ++kx)
                        acc = fma((double)xs[c3][2 * r + ky][2 * cc + kx],
                                  (double)wp[c3 * 16 + ky * 4 + kx], acc);
            double m = stats[ci] * (1.0 / 1048576.0);
            double var = stats[16 + ci] * (1.0 / 1048576.0) - m * m;
            double sc = (double)eg1[ci] / sqrt(var + EPS);
            double sh = (double)ebt1[ci] - m * sc;
            double v = fma(acc, sc, sh);
            val = (float)(v > 0.0 ? v : 0.0);
        }
        h1s[ci][r][cc] = val;
    }
    __syncthreads();
    int s = tid & 63, ly = s >> 3, lx = s & 7;
    int cog = (tid >> 6) * 8;
    double acc[8];
#pragma unroll
    for (int j = 0; j < 8; ++j) acc[j] = (double)eb2[cog + j];
    for (int ci = 0; ci < 16; ++ci) {
        float t[16];
#pragma unroll
        for (int ky = 0; ky < 4; ++ky)
#pragma unroll
            for (int kx = 0; kx < 4; ++kx)
                t[ky * 4 + kx] = h1s[ci][2 * ly + ky][2 * lx + kx];
#pragma unroll
        for (int j = 0; j < 8; ++j) {
            const float* wp = eW2 + ((cog + j) * 16 + ci) * 16;
#pragma unroll
            for (int k = 0; k < 16; ++k)
                acc[j] = fma((double)t[k], (double)wp[k], acc[j]);
        }
    }
    int oy = oy0 + ly, ox = ox0 + lx;
#pragma unroll
    for (int j = 0; j < 8; ++j)
        h2[(size_t)(n * 32 + cog + j) * 4096 + oy * 64 + ox] = (float)acc[j];
}

// ---- generic single-pass BN stats over f32. grid(C,N) ----
__global__ void bn_stats_k(const float* __restrict__ y, double* __restrict__ sum,
                           double* __restrict__ sq, int C, int HW) {
    int c = blockIdx.x, n = blockIdx.y;
    const float* p = y + (size_t)(n * C + c) * HW;
    double s = 0.0, s2 = 0.0;
    for (int i = threadIdx.x; i < HW; i += blockDim.x) {
        double v = (double)p[i];
        s += v;
        s2 = fma(v, v, s2);
    }
    block_reduce2(s, s2, &sum[c], &sq[c]);
}

// ---- BN + ReLU in place (f32 data, f64 math). grid(HW/256,C,N) ----
__global__ void bn_relu_k(float* __restrict__ y, const double* __restrict__ sum,
                          const double* __restrict__ sq, int HW, double invCnt) {
    int hw = blockIdx.x * blockDim.x + threadIdx.x;
    int c = blockIdx.y, n = blockIdx.z, C = gridDim.y;
    double m = sum[c] * invCnt;
    double var = sq[c] * invCnt - m * m;
    // gamma/beta folded by caller via textures? no — pass arrays:
    (void)var;
    // (specialized below — this generic body unused)
    (void)m; (void)hw; (void)n; (void)C; (void)HW; (void)y;
}

// actual BN+activation kernels (gamma/beta needed)
template <int MODE>  // 0 relu in-place, 1 tanh -> out
__global__ void bn_apply_k(float* __restrict__ y, const double* __restrict__ sum,
                           const double* __restrict__ sq, const float* __restrict__ g,
                           const float* __restrict__ b, float* __restrict__ dst,
                           int HW, double invCnt) {
    int hw = blockIdx.x * blockDim.x + threadIdx.x;
    int c = blockIdx.y, n = blockIdx.z, C = gridDim.y;
    double m = sum[c] * invCnt;
    double var = sq[c] * invCnt - m * m;
    double sc = (double)g[c] / sqrt(var + EPS);
    double sh = (double)b[c] - m * sc;
    size_t i = (size_t)(n * C + c) * HW + hw;
    double val = fma((double)y[i], sc, sh);
    if (MODE == 0) y[i] = (float)(val > 0.0 ? val : 0.0);
    else           dst[i] = (float)tanh(val);
}

// ---- conv3: h2 f32 -> z3 f32, LDS-staged. grid(16,64) ----
__global__ void conv3_k(const float* __restrict__ h2, const float* __restrict__ w,
                        const float* __restrict__ bias, float* __restrict__ z3) {
    __shared__ float hs[32][6][66];
    int c = blockIdx.x, n = blockIdx.y, tid = threadIdx.x;
    int iyBase = 4 * c - 1;
    for (int idx = tid; idx < 32 * 6 * 66; idx += 256) {
        int ch = idx / 396, rem = idx - ch * 396, r = rem / 66, cc = rem - r * 66;
        int iy = iyBase + r, ix = cc - 1;
        float v = 0.f;
        if ((unsigned)iy < 64u && (unsigned)ix < 64u)
            v = h2[(size_t)(n * 32 + ch) * 4096 + iy * 64 + ix];
        hs[ch][r][cc] = v;
    }
    __syncthreads();
    int s = tid & 63;
    int oy = 2 * c + (s >> 5), ox = s & 31;
    int lr = 2 * (s >> 5), lc = 2 * ox;
    int cog = (tid >> 6) * 16;
    double acc[16];
#pragma unroll
    for (int j = 0; j < 16; ++j) acc[j] = (double)bias[cog + j];
    for (int ci = 0; ci < 32; ++ci) {
        float t[16];
#pragma unroll
        for (int ky = 0; ky < 4; ++ky)
#pragma unroll
            for (int kx = 0; kx < 4; ++kx)
                t[ky * 4 + kx] = hs[ci][lr + ky][lc + kx];
#pragma unroll
        for (int j = 0; j < 16; ++j) {
            const float* wp = w + ((cog + j) * 32 + ci) * 16;
#pragma unroll
            for (int k = 0; k < 16; ++k)
                acc[j] = fma((double)t[k], (double)wp[k], acc[j]);
        }
    }
#pragma unroll
    for (int j = 0; j < 16; ++j)
        z3[(size_t)(n * 64 + cog + j) * 1024 + oy * 32 + ox] = (float)acc[j];
}

// ---- scc precompute: scc[k] = np_sum64(c^2) ----
__device__ __forceinline__ float np_sum64(const float* a) {
    float r[8];
#pragma unroll
    for (int j = 0; j < 8; ++j) r[j] = a[j];
#pragma unroll
    for (int m = 1; m < 8; ++m)
#pragma unroll
        for (int j = 0; j < 8; ++j) r[j] += a[m * 8 + j];
    return ((r[0] + r[1]) + (r[2] + r[3])) + ((r[4] + r[5]) + (r[6] + r[7]));
}

__global__ void scc_k(const float* __restrict__ cb, float* __restrict__ scc) {
    int k = blockIdx.x * blockDim.x + threadIdx.x;
    if (k >= 512) return;
    const float* c = cb + (k << 6);
    float cc[64];
#pragma unroll
    for (int d = 0; d < 64; ++d) cc[d] = c[d] * c[d];
    scc[k] = np_sum64(cc);
}

// ---- VQ: np-mimic f32 argmin; exact f64 dist of chosen code -> loss ----
__global__ void vq_k(const float* __restrict__ z, const float* __restrict__ cb,
                     const float* __restrict__ scc, float* __restrict__ quant,
                     double* __restrict__ lossAcc) {
    int p = blockIdx.x * blockDim.x + threadIdx.x;
    int n = p >> 10, hw = p & 1023;
    const float* zp = z + (size_t)n * 65536 + hw;
    float z32[64], zz[64];
#pragma unroll
    for (int d = 0; d < 64; ++d) {
        z32[d] = zp[d * 1024];
        zz[d] = z32[d] * z32[d];
    }
    float sz = np_sum64(zz);
    float bestf = 3.4e38f;
    int bif = 0;
    for (int k = 0; k < 512; ++k) {
        const float* c = cb + (k << 6);
        float dot = 0.f;
#pragma unroll
        for (int d = 0; d < 64; ++d) dot = fmaf(z32[d], c[d], dot);
        float distf = (sz + scc[k]) - 2.f * dot;
        if (distf < bestf) { bestf = distf; bif = k; }
    }
    const float* c = cb + (bif << 6);
    float* qp = quant + (size_t)n * 65536 + hw;
    double dist = 0.0;
#pragma unroll
    for (int d = 0; d < 64; ++d) {
        double diff = (double)z32[d] - (double)c[d];
        dist = fma(diff, diff, dist);
        qp[d * 1024] = c[d];
    }
    double s = dist;
#pragma unroll
    for (int o = 32; o; o >>= 1) s += __shfl_down(s, o);
    if ((threadIdx.x & 63) == 0) atomicAdd(lossAcc, s);
}

__global__ void finalize_loss_k(const double* lossAcc, float* out, int idx) {
    if (threadIdx.x == 0 && blockIdx.x == 0)
        out[idx] = (float)(2.0 * (*lossAcc) / 4194304.0);
}

// ---- deconv1: quant[64][32][32] -> d1[32][64][64]. grid(16,64) ----
__global__ void deconv1_k(const float* __restrict__ in, const float* __restrict__ w,
                          const float* __restrict__ bias, float* __restrict__ out) {
    __shared__ float ls[64][4][34];
    int b = blockIdx.x, n = blockIdx.y, tid = threadIdx.x;
    int qy0 = 2 * b;
    for (int idx = tid; idx < 64 * 4 * 34; idx += 256) {
        int ch = idx / 136, rem = idx - ch * 136, r = rem / 34, cc = rem - r * 34;
        int iy = qy0 - 1 + r, ix = cc - 1;
        float v = 0.f;
        if ((unsigned)iy < 32u && (unsigned)ix < 32u)
            v = in[(size_t)(n * 64 + ch) * 1024 + iy * 32 + ix];
        ls[ch][r][cc] = v;
    }
    __syncthreads();
    int pt = tid & 63;
    int qy = qy0 + (pt >> 5), qx = pt & 31;
    int cog = (tid >> 6) * 8;
    int rb = qy - qy0;                       // LDS row of iy=qy-1
    float acc[2][2][8];
#pragma unroll
    for (int dy = 0; dy < 2; ++dy)
#pragma unroll
        for (int dx = 0; dx < 2; ++dx)
#pragma unroll
            for (int j = 0; j < 8; ++j) acc[dy][dx][j] = bias[cog + j];
    for (int ci = 0; ci < 64; ++ci) {
        float v[3][3];
#pragma unroll
        for (int ry = 0; ry < 3; ++ry)
#pragma unroll
            for (int rx = 0; rx < 3; ++rx)
                v[ry][rx] = ls[ci][rb + ry][qx + rx];
#pragma unroll
        for (int j = 0; j < 8; ++j) {
            const float* wp = w + ((cog + j) * 64 + ci) * 16;
            acc[0][0][j] += v[0][0]*wp[0] + v[0][1]*wp[2] + v[1][0]*wp[8]  + v[1][1]*wp[10];
            acc[0][1][j] += v[0][1]*wp[1] + v[0][2]*wp[3] + v[1][1]*wp[9]  + v[1][2]*wp[11];
            acc[1][0][j] += v[1][0]*wp[4] + v[1][1]*wp[6] + v[2][0]*wp[12] + v[2][1]*wp[14];
            acc[1][1][j] += v[1][1]*wp[5] + v[1][2]*wp[7] + v[2][1]*wp[13] + v[2][2]*wp[15];
        }
    }
#pragma unroll
    for (int dy = 0; dy < 2; ++dy)
#pragma unroll
        for (int dx = 0; dx < 2; ++dx)
#pragma unroll
            for (int j = 0; j < 8; ++j)
                out[(size_t)(n * 32 + cog + j) * 4096 + (2*qy+dy) * 64 + 2*qx+dx]
                    = acc[dy][dx][j];
}

// ---- deconv2: d1[32][64][64] -> d2[16][128][128]. grid(64,64) ----
__global__ void deconv2_k(const float* __restrict__ in, const float* __restrict__ w,
                          const float* __restrict__ bias, float* __restrict__ out) {
    __shared__ float ls[32][3][66];
    int b = blockIdx.x, n = blockIdx.y, tid = threadIdx.x;
    for (int idx = tid; idx < 32 * 3 * 66; idx += 256) {
        int ch = idx / 198, rem = idx - ch * 198, r = rem / 66, cc = rem - r * 66;
        int iy = b - 1 + r, ix = cc - 1;
        float v = 0.f;
        if ((unsigned)iy < 64u && (unsigned)ix < 64u)
            v = in[(size_t)(n * 32 + ch) * 4096 + iy * 64 + ix];
        ls[ch][r][cc] = v;
    }
    __syncthreads();
    int pt = tid & 63;
    int qx = pt;
    int cog = (tid >> 6) * 4;
    float acc[2][2][4];
#pragma unroll
    for (int dy = 0; dy < 2; ++dy)
#pragma unroll
        for (int dx = 0; dx < 2; ++dx)
#pragma unroll
            for (int j = 0; j < 4; ++j) acc[dy][dx][j] = bias[cog + j];
    for (int ci = 0; ci < 32; ++ci) {
        float v[3][3];
#pragma unroll
        for (int ry = 0; ry < 3; ++ry)
#pragma unroll
            for (int rx = 0; rx < 3; ++rx)
                v[ry][rx] = ls[ci][ry][qx + rx];
#pragma unroll
        for (int j = 0; j < 4; ++j) {
            const float* wp = w + ((cog + j) * 32 + ci) * 16;
            acc[0][0][j] += v[0][0]*wp[0] + v[0][1]*wp[2] + v[1][0]*wp[8]  + v[1][1]*wp[10];
            acc[0][1][j] += v[0][1]*wp[1] + v[0][2]*wp[3] + v[1][1]*wp[9]  + v[1][2]*wp[11];
            acc[1][0][j] += v[1][0]*wp[4] + v[1][1]*wp[6] + v[2][0]*wp[12] + v[2][1]*wp[14];
            acc[1][1][j] += v[1][1]*wp[5] + v[1][2]*wp[7] + v[2][1]*wp[13] + v[2][2]*wp[15];
        }
    }
#pragma unroll
    for (int dy = 0; dy < 2; ++dy)
#pragma unroll
        for (int dx = 0; dx < 2; ++dx)
#pragma unroll
            for (int j = 0; j < 4; ++j)
                out[(size_t)(n * 16 + cog + j) * 16384 + (2*b+dy) * 128 + 2*qx+dx]
                    = acc[dy][dx][j];
}

// ---- deconv3: d2[16][128][128] -> d3[3][256][256]. grid(64,64) ----
__global__ void deconv3_k(const float* __restrict__ in, const float* __restrict__ w,
                          const float* __restrict__ bias, float* __restrict__ out) {
    __shared__ float ls[16][4][130];
    int b = blockIdx.x, n = blockIdx.y, tid = threadIdx.x;
    int qy0 = 2 * b;
    for (int idx = tid; idx < 16 * 4 * 130; idx += 256) {
        int ch = idx / 520, rem = idx - ch * 520, r = rem / 130, cc = rem - r * 130;
        int iy = qy0 - 1 + r, ix = cc - 1;
        float v = 0.f;
        if ((unsigned)iy < 128u && (unsigned)ix < 128u)
            v = in[(size_t)(n * 16 + ch) * 16384 + iy * 128 + ix];
        ls[ch][r][cc] = v;
    }
    __syncthreads();
    int qy = qy0 + (tid >> 7), qx = tid & 127;
    int rb = qy - qy0;
    float acc[2][2][3];
#pragma unroll
    for (int dy = 0; dy < 2; ++dy)
#pragma unroll
        for (int dx = 0; dx < 2; ++dx)
#pragma unroll
            for (int j = 0; j < 3; ++j) acc[dy][dx][j] = bias[j];
    for (int ci = 0; ci < 16; ++ci) {
        float v[3][3];
#pragma unroll
        for (int ry = 0; ry < 3; ++ry)
#pragma unroll
            for (int rx = 0; rx < 3; ++rx)
                v[ry][rx] = ls[ci][rb + ry][qx + rx];
#pragma unroll
        for (int j = 0; j < 3; ++j) {
            const float* wp = w + (j * 16 + ci) * 16;
            acc[0][0][j] += v[0][0]*wp[0] + v[0][1]*wp[2] + v[1][0]*wp[8]  + v[1][1]*wp[10];
            acc[0][1][j] += v[0][1]*wp[1] + v[0][2]*wp[3] + v[1][1]*wp[9]  + v[1][2]*wp[11];
            acc[1][0][j] += v[1][0]*wp[4] + v[1][1]*wp[6] + v[2][0]*wp[12] + v[2][1]*wp[14];
            acc[1][1][j] += v[1][1]*wp[5] + v[1][2]*wp[7] + v[2][1]*wp[13] + v[2][2]*wp[15];
        }
    }
#pragma unroll
    for (int dy = 0; dy < 2; ++dy)
#pragma unroll
        for (int dx = 0; dx < 2; ++dx)
#pragma unroll
            for (int j = 0; j < 3; ++j)
                out[(size_t)(n * 3 + j) * 65536 + (2*qy+dy) * 256 + 2*qx+dx]
                    = acc[dy][dx][j];
}

extern "C" void kernel_launch(void* const* d_in, const int* in_sizes, int n_in,
                              void* d_out, int out_size, void* d_ws, size_t ws_size,
                              hipStream_t stream) {
    const float* x   = (const float*)d_in[0];
    const float* cb  = (const float*)d_in[1];
    const float* eW1 = (const float*)d_in[2];
    const float* eb1 = (const float*)d_in[3];
    const float* eg1 = (const float*)d_in[4];
    const float* ebt1= (const float*)d_in[5];
    const float* eW2 = (const float*)d_in[6];
    const float* eb2 = (const float*)d_in[7];
    const float* eg2 = (const float*)d_in[8];
    const float* ebt2= (const float*)d_in[9];
    const float* eW3 = (const float*)d_in[10];
    const float* eb3 = (const float*)d_in[11];
    const float* eg3 = (const float*)d_in[12];
    const float* ebt3= (const float*)d_in[13];
    const float* dW1 = (const float*)d_in[14];
    const float* db1 = (const float*)d_in[15];
    const float* dg1 = (const float*)d_in[16];
    const float* dbt1= (const float*)d_in[17];
    const float* dW2 = (const float*)d_in[18];
    const float* db2 = (const float*)d_in[19];
    const float* dg2 = (const float*)d_in[20];
    const float* dbt2= (const float*)d_in[21];
    const float* dW3 = (const float*)d_in[22];
    const float* db3 = (const float*)d_in[23];
    const float* dg3 = (const float*)d_in[24];
    const float* dbt3= (const float*)d_in[25];

    float* out = (float*)d_out;
    char* ws = (char*)d_ws;
    float* h2    = (float*)ws;                        // [0, 33.5M)
    float* z     = (float*)(ws + 33554432);           // [33.5M, 50.3M)
    float* quant = (float*)(ws + 50331648);           // [50.3M, 67.1M)
    float* d1    = (float*)(ws + 67108864);           // [67.1M, 100.7M)
    float* d2    = (float*)ws;                        // [0, 67.1M)
    float* d3    = (float*)(ws + 67108864);           // [67.1M, 117.4M)
    double* stats = (double*)(ws + 117440512);        // 327 doubles
    double* lossAcc = stats + 326;
    float* scc   = (float*)(ws + 117443200);          // 512 f32
    dim3 B(256);

    zero_stats_k<<<2, B, 0, stream>>>(stats, 327);
    scc_k<<<2, B, 0, stream>>>(cb, scc);

    // encoder
    conv1_stats_k<<<dim3(64, 64), B, 0, stream>>>(x, eW1, eb1, stats + 0);
    fused_conv2_k<<<dim3(64, 64), B, 0, stream>>>(x, eW1, eb1, eg1, ebt1, eW2, eb2,
                                                  stats + 0, h2);
    bn_stats_k<<<dim3(32, 64), B, 0, stream>>>(h2, stats + 32, stats + 64, 32, 4096);
    bn_apply_k<0><<<dim3(16, 32, 64), B, 0, stream>>>(h2, stats + 32, stats + 64,
                                                      eg2, ebt2, nullptr, 4096,
                                                      1.0 / 262144.0);
    conv3_k<<<dim3(16, 64), B, 0, stream>>>(h2, eW3, eb3, z);
    bn_stats_k<<<dim3(64, 64), B, 0, stream>>>(z, stats + 96, stats + 160, 64, 1024);
    bn_apply_k<0><<<dim3(4, 64, 64), B, 0, stream>>>(z, stats + 96, stats + 160,
                                                     eg3, ebt3, nullptr, 1024,
                                                     1.0 / 65536.0);
    // VQ
    vq_k<<<256, B, 0, stream>>>(z, cb, scc, quant, lossAcc);
    finalize_loss_k<<<1, 64, 0, stream>>>(lossAcc, out, out_size - 1);

    // decoder
    deconv1_k<<<dim3(16, 64), B, 0, stream>>>(quant, dW1, db1, d1);
    bn_stats_k<<<dim3(32, 64), B, 0, stream>>>(d1, stats + 224, stats + 256, 32, 4096);
    bn_apply_k<0><<<dim3(16, 32, 64), B, 0, stream>>>(d1, stats + 224, stats + 256,
                                                      dg1, dbt1, nullptr, 4096,
                                                      1.0 / 262144.0);
    deconv2_k<<<dim3(64, 64), B, 0, stream>>>(d1, dW2, db2, d2);
    bn_stats_k<<<dim3(16, 64), B, 0, stream>>>(d2, stats + 288, stats + 304, 16, 16384);
    bn_apply_k<0><<<dim3(64, 16, 64), B, 0, stream>>>(d2, stats + 288, stats + 304,
                                                      dg2, dbt2, nullptr, 16384,
                                                      1.0 / 1048576.0);
    deconv3_k<<<dim3(64, 64), B, 0, stream>>>(d2, dW3, db3, d3);
    bn_stats_k<<<dim3(3, 64), B, 0, stream>>>(d3, stats + 320, stats + 323, 3, 65536);
    bn_apply_k<1><<<dim3(256, 3, 64), B, 0, stream>>>(d3, stats + 320, stats + 323,
                                                      dg3, dbt3, out, 65536,
                                                      1.0 / 4194304.0);
}

// Round 12
// 1870.797 us; speedup vs baseline: 5.4957x; 1.3487x over previous
//
#include <hip/hip_runtime.h>
#include <hip/hip_bf16.h>

// ---------------------------------------------------------------------------
// VQ-VAE forward — R12 (R10 passed @2523us; R11's pre-BN h1 rounding flipped
// an argmin -> reverted; R11's bit-identical BN folds kept).
//  * Layer 1: R10-exact numerics. conv1 f64 acc; BN1 applied to unrounded
//    f64 acc inside fused_conv2 (recompute). Stats via register-accumulating
//    atomic-free pass (was 735us of serialized f64 atomics).
//  * BN2/3/4/5 folded bit-identically into conv3/vq/deconv2/deconv3 staging.
// ws layout (R10): h2@0 33.5M | z@33.5M | quant@50.3M | d1@67.1M |
//   d2@0 67.1M | d3@67.1M 50.3M | stats f64[327]@117,440,512 |
//   scc f32[512]@117,443,200 | partials f64[512*32]@ws+0 (dead before h2)
// stats: c1 sum@0 sq@16 | bn2 @32/@64 | bn3 @96/@160 | bn4 @224/@256
//        bn5 @288/@304 | bn6 @320/@323 | loss @326
// ---------------------------------------------------------------------------

#define EPS 1e-5

__global__ void zero_stats_k(double* s, int n) {
    int i = blockIdx.x * blockDim.x + threadIdx.x;
    if (i < n) s[i] = 0.0;
}

__device__ __forceinline__ void block_reduce2(double v1, double v2,
                                              double* t1, double* t2) {
#pragma unroll
    for (int o = 32; o; o >>= 1) {
        v1 += __shfl_down(v1, o);
        v2 += __shfl_down(v2, o);
    }
    __shared__ double ls[4][2];
    int wid = threadIdx.x >> 6, lane = threadIdx.x & 63;
    if (lane == 0) { ls[wid][0] = v1; ls[wid][1] = v2; }
    __syncthreads();
    if (threadIdx.x == 0) {
        atomicAdd(t1, ls[0][0] + ls[1][0] + ls[2][0] + ls[3][0]);
        atomicAdd(t2, ls[0][1] + ls[1][1] + ls[2][1] + ls[3][1]);
    }
    __syncthreads();
}

// ---- conv1 stats: atomic-free. grid(8 bands, 64 n), block 256.
// Each block: 8 strips (2 out-rows each), all 16 cos in register acc,
// one shuffle-reduce, non-atomic partials[(n*8+band)*32 + j].
__global__ void conv1_stats_k(const float* __restrict__ x, const float* __restrict__ w,
                              const float* __restrict__ bias,
                              double* __restrict__ partials) {
    __shared__ float xs[3][6][258];
    __shared__ float wls[768];
    __shared__ float bls[16];
    __shared__ double lsw[4][32];
    int band = blockIdx.x, n = blockIdx.y, tid = threadIdx.x;
    for (int i = tid; i < 768; i += 256) wls[i] = w[i];
    if (tid < 16) bls[tid] = bias[tid];
    double sums[16], sqs[16];
#pragma unroll
    for (int j = 0; j < 16; ++j) { sums[j] = 0.0; sqs[j] = 0.0; }
    for (int s8 = 0; s8 < 8; ++s8) {
        int strip = band * 8 + s8;
        int iyBase = 4 * strip - 1;
        __syncthreads();
        for (int idx = tid; idx < 3 * 6 * 258; idx += 256) {
            int ch = idx / 1548, rem = idx - ch * 1548, r = rem / 258, cc = rem - r * 258;
            int iy = iyBase + r, ix = cc - 1;
            float v = 0.f;
            if ((unsigned)iy < 256u && (unsigned)ix < 256u)
                v = x[(size_t)(n * 3 + ch) * 65536 + iy * 256 + ix];
            xs[ch][r][cc] = v;
        }
        __syncthreads();
        int lr = 2 * (tid >> 7), lc = 2 * (tid & 127);
        float win[3][4][4];
#pragma unroll
        for (int ci = 0; ci < 3; ++ci)
#pragma unroll
            for (int ky = 0; ky < 4; ++ky)
#pragma unroll
                for (int kx = 0; kx < 4; ++kx)
                    win[ci][ky][kx] = xs[ci][lr + ky][lc + kx];
#pragma unroll
        for (int co = 0; co < 16; ++co) {
            double acc = (double)bls[co];
            const float* wp = &wls[co * 48];
#pragma unroll
            for (int ci = 0; ci < 3; ++ci)
#pragma unroll
                for (int ky = 0; ky < 4; ++ky)
#pragma unroll
                    for (int kx = 0; kx < 4; ++kx)
                        acc = fma((double)win[ci][ky][kx],
                                  (double)wp[ci * 16 + ky * 4 + kx], acc);
            sums[co] += acc;
            sqs[co] = fma(acc, acc, sqs[co]);
        }
    }
    double val[32];
#pragma unroll
    for (int j = 0; j < 16; ++j) { val[j] = sums[j]; val[16 + j] = sqs[j]; }
#pragma unroll
    for (int o = 32; o; o >>= 1)
#pragma unroll
        for (int j = 0; j < 32; ++j) val[j] += __shfl_down(val[j], o);
    int wid = tid >> 6, lane = tid & 63;
    if (lane == 0)
#pragma unroll
        for (int j = 0; j < 32; ++j) lsw[wid][j] = val[j];
    __syncthreads();
    if (tid < 32) {
        double p = lsw[0][tid] + lsw[1][tid] + lsw[2][tid] + lsw[3][tid];
        partials[(size_t)(n * 8 + band) * 32 + tid] = p;
    }
}

// sum 512 block-partials -> stats[0..31] (sum@0-15, sq@16-31)
__global__ void reduce_stats_k(const double* __restrict__ partials,
                               double* __restrict__ stats) {
    int t = threadIdx.x;
    if (t < 32) {
        double s = 0.0;
        for (int i = 0; i < 512; ++i) s += partials[(size_t)i * 32 + t];
        stats[t] = s;
    }
}

// ---- fused conv1+BN1+ReLU -> conv2 -> h2 raw f32 (R10-exact). grid(64,64) ----
__global__ void fused_conv2_k(const float* __restrict__ x, const float* __restrict__ eW1,
                              const float* __restrict__ eb1, const float* __restrict__ eg1,
                              const float* __restrict__ ebt1, const float* __restrict__ eW2,
                              const float* __restrict__ eb2, const double* __restrict__ stats,
                              float* __restrict__ h2) {
    __shared__ float xs[3][38][38];
    __shared__ float h1s[16][18][18];
    int tile = blockIdx.x, n = blockIdx.y, tid = threadIdx.x;
    int ty = tile >> 3, tx = tile & 7;
    int oy0 = 8 * ty, ox0 = 8 * tx;
    int iyBase = 32 * ty - 3, ixBase = 32 * tx - 3;
    for (int idx = tid; idx < 3 * 38 * 38; idx += 256) {
        int ch = idx / 1444, rem = idx - ch * 1444, r = rem / 38, cc = rem - r * 38;
        int iy = iyBase + r, ix = ixBase + cc;
        float v = 0.f;
        if ((unsigned)iy < 256u && (unsigned)ix < 256u)
            v = x[(size_t)(n * 3 + ch) * 65536 + iy * 256 + ix];
        xs[ch][r][cc] = v;
    }
    __syncthreads();
    int hy0 = 16 * ty - 1, hx0 = 16 * tx - 1;
    for (int idx = tid; idx < 16 * 18 * 18; idx += 256) {
        int ci = idx / 324, rem = idx - ci * 324, r = rem / 18, cc = rem - r * 18;
        int hy = hy0 + r, hx = hx0 + cc;
        float val = 0.f;
        if ((unsigned)hy < 128u && (unsigned)hx < 128u) {
            double acc = (double)eb1[ci];
            const float* wp = eW1 + ci * 48;
#pragma unroll
            for (int c3 = 0; c3 < 3; ++c3)
#pragma unroll
                for (int ky = 0; ky < 4; ++ky)
#pragma unroll
                    for (int kx = 0; kx < 4; ++kx)
                        acc = fma((double)xs[c3][2 * r + ky][2 * cc + kx],
                                  (double)wp[c3 * 16 + ky * 4 + kx], acc);
            double m = stats[ci] * (1.0 / 1048576.0);
            double var = stats[16 + ci] * (1.0 / 1048576.0) - m * m;
            double sc = (double)eg1[ci] / sqrt(var + EPS);
            double sh = (double)ebt1[ci] - m * sc;
            double v = fma(acc, sc, sh);
            val = (float)(v > 0.0 ? v : 0.0);
        }
        h1s[ci][r][cc] = val;
    }
    __syncthreads();
    int s = tid & 63, ly = s >> 3, lx = s & 7;
    int cog = (tid >> 6) * 8;
    double acc[8];
#pragma unroll
    for (int j = 0; j < 8; ++j) acc[j] = (double)eb2[cog + j];
    for (int ci = 0; ci < 16; ++ci) {
        float t[16];
#pragma unroll
        for (int ky = 0; ky < 4; ++ky)
#pragma unroll
            for (int kx = 0; kx < 4; ++kx)
                t[ky * 4 + kx] = h1s[ci][2 * ly + ky][2 * lx + kx];
#pragma unroll
        for (int j = 0; j < 8; ++j) {
            const float* wp = eW2 + ((cog + j) * 16 + ci) * 16;
#pragma unroll
            for (int k = 0; k < 16; ++k)
                acc[j] = fma((double)t[k], (double)wp[k], acc[j]);
        }
    }
    int oy = oy0 + ly, ox = ox0 + lx;
#pragma unroll
    for (int j = 0; j < 8; ++j)
        h2[(size_t)(n * 32 + cog + j) * 4096 + oy * 64 + ox] = (float)acc[j];
}

// ---- generic BN stats over raw f32. grid(C,N) ----
__global__ void bn_stats_k(const float* __restrict__ y, double* __restrict__ sum,
                           double* __restrict__ sq, int C, int HW) {
    int c = blockIdx.x, n = blockIdx.y;
    const float* p = y + (size_t)(n * C + c) * HW;
    double s = 0.0, s2 = 0.0;
    for (int i = threadIdx.x; i < HW; i += blockDim.x) {
        double v = (double)p[i];
        s += v;
        s2 = fma(v, v, s2);
    }
    block_reduce2(s, s2, &sum[c], &sq[c]);
}

__device__ __forceinline__ void bn_consts(int tid, int C, const double* sum,
                                          const double* sq, const float* g,
                                          const float* b, double invCnt,
                                          double* scd, double* shd) {
    if (tid < C) {
        double m = sum[tid] * invCnt;
        double var = sq[tid] * invCnt - m * m;
        double sc = (double)g[tid] / sqrt(var + EPS);
        scd[tid] = sc;
        shd[tid] = (double)b[tid] - m * sc;
    }
}

// ---- conv3: BN2+ReLU(h2) staged -> z raw f32. grid(16,64) ----
__global__ void conv3_k(const float* __restrict__ h2, const float* __restrict__ w,
                        const float* __restrict__ bias, const float* __restrict__ eg2,
                        const float* __restrict__ ebt2, const double* __restrict__ sum2,
                        const double* __restrict__ sq2, float* __restrict__ z3) {
    __shared__ float hs[32][6][66];
    __shared__ double scd[32], shd[32];
    int c = blockIdx.x, n = blockIdx.y, tid = threadIdx.x;
    bn_consts(tid, 32, sum2, sq2, eg2, ebt2, 1.0 / 262144.0, scd, shd);
    __syncthreads();
    int iyBase = 4 * c - 1;
    for (int idx = tid; idx < 32 * 6 * 66; idx += 256) {
        int ch = idx / 396, rem = idx - ch * 396, r = rem / 66, cc = rem - r * 66;
        int iy = iyBase + r, ix = cc - 1;
        float val = 0.f;
        if ((unsigned)iy < 64u && (unsigned)ix < 64u) {
            double v = fma((double)h2[(size_t)(n * 32 + ch) * 4096 + iy * 64 + ix],
                           scd[ch], shd[ch]);
            val = v > 0.0 ? (float)v : 0.f;
        }
        hs[ch][r][cc] = val;
    }
    __syncthreads();
    int s = tid & 63;
    int oy = 2 * c + (s >> 5), ox = s & 31;
    int lr = 2 * (s >> 5), lc = 2 * ox;
    int cog = (tid >> 6) * 16;
    double acc[16];
#pragma unroll
    for (int j = 0; j < 16; ++j) acc[j] = (double)bias[cog + j];
    for (int ci = 0; ci < 32; ++ci) {
        float t[16];
#pragma unroll
        for (int ky = 0; ky < 4; ++ky)
#pragma unroll
            for (int kx = 0; kx < 4; ++kx)
                t[ky * 4 + kx] = hs[ci][lr + ky][lc + kx];
#pragma unroll
        for (int j = 0; j < 16; ++j) {
            const float* wp = w + ((cog + j) * 32 + ci) * 16;
#pragma unroll
            for (int k = 0; k < 16; ++k)
                acc[j] = fma((double)t[k], (double)wp[k], acc[j]);
        }
    }
#pragma unroll
    for (int j = 0; j < 16; ++j)
        z3[(size_t)(n * 64 + cog + j) * 1024 + oy * 32 + ox] = (float)acc[j];
}

__device__ __forceinline__ float np_sum64(const float* a) {
    float r[8];
#pragma unroll
    for (int j = 0; j < 8; ++j) r[j] = a[j];
#pragma unroll
    for (int m = 1; m < 8; ++m)
#pragma unroll
        for (int j = 0; j < 8; ++j) r[j] += a[m * 8 + j];
    return ((r[0] + r[1]) + (r[2] + r[3])) + ((r[4] + r[5]) + (r[6] + r[7]));
}

__global__ void scc_k(const float* __restrict__ cb, float* __restrict__ scc) {
    int k = blockIdx.x * blockDim.x + threadIdx.x;
    if (k >= 512) return;
    const float* c = cb + (k << 6);
    float cc[64];
#pragma unroll
    for (int d = 0; d < 64; ++d) cc[d] = c[d] * c[d];
    scc[k] = np_sum64(cc);
}

// ---- VQ: BN3+ReLU in-register; np-mimic f32 argmin; f64 loss ----
__global__ void vq_k(const float* __restrict__ zraw, const float* __restrict__ cb,
                     const float* __restrict__ scc, const float* __restrict__ eg3,
                     const float* __restrict__ ebt3, const double* __restrict__ sum3,
                     const double* __restrict__ sq3, float* __restrict__ quant,
                     double* __restrict__ lossAcc) {
    __shared__ double scd[64], shd[64];
    bn_consts(threadIdx.x, 64, sum3, sq3, eg3, ebt3, 1.0 / 65536.0, scd, shd);
    __syncthreads();
    int p = blockIdx.x * blockDim.x + threadIdx.x;
    int n = p >> 10, hw = p & 1023;
    const float* zp = zraw + (size_t)n * 65536 + hw;
    float z32[64], zz[64];
#pragma unroll
    for (int d = 0; d < 64; ++d) {
        double v = fma((double)zp[d * 1024], scd[d], shd[d]);
        z32[d] = v > 0.0 ? (float)v : 0.f;
        zz[d] = z32[d] * z32[d];
    }
    float sz = np_sum64(zz);
    float bestf = 3.4e38f;
    int bif = 0;
    for (int k = 0; k < 512; ++k) {
        const float* c = cb + (k << 6);
        float dot = 0.f;
#pragma unroll
        for (int d = 0; d < 64; ++d) dot = fmaf(z32[d], c[d], dot);
        float distf = (sz + scc[k]) - 2.f * dot;
        if (distf < bestf) { bestf = distf; bif = k; }
    }
    const float* c = cb + (bif << 6);
    float* qp = quant + (size_t)n * 65536 + hw;
    double dist = 0.0;
#pragma unroll
    for (int d = 0; d < 64; ++d) {
        double diff = (double)z32[d] - (double)c[d];
        dist = fma(diff, diff, dist);
        qp[d * 1024] = c[d];
    }
    double s = dist;
#pragma unroll
    for (int o = 32; o; o >>= 1) s += __shfl_down(s, o);
    if ((threadIdx.x & 63) == 0) atomicAdd(lossAcc, s);
}

__global__ void finalize_loss_k(const double* lossAcc, float* out, int idx) {
    if (threadIdx.x == 0 && blockIdx.x == 0)
        out[idx] = (float)(2.0 * (*lossAcc) / 4194304.0);
}

// ---- deconv1: quant -> d1 raw. grid(16,64) ----
__global__ void deconv1_k(const float* __restrict__ in, const float* __restrict__ w,
                          const float* __restrict__ bias, float* __restrict__ out) {
    __shared__ float ls[64][4][34];
    int b = blockIdx.x, n = blockIdx.y, tid = threadIdx.x;
    int qy0 = 2 * b;
    for (int idx = tid; idx < 64 * 4 * 34; idx += 256) {
        int ch = idx / 136, rem = idx - ch * 136, r = rem / 34, cc = rem - r * 34;
        int iy = qy0 - 1 + r, ix = cc - 1;
        float v = 0.f;
        if ((unsigned)iy < 32u && (unsigned)ix < 32u)
            v = in[(size_t)(n * 64 + ch) * 1024 + iy * 32 + ix];
        ls[ch][r][cc] = v;
    }
    __syncthreads();
    int pt = tid & 63;
    int qy = qy0 + (pt >> 5), qx = pt & 31;
    int cog = (tid >> 6) * 8;
    int rb = qy - qy0;
    float acc[2][2][8];
#pragma unroll
    for (int dy = 0; dy < 2; ++dy)
#pragma unroll
        for (int dx = 0; dx < 2; ++dx)
#pragma unroll
            for (int j = 0; j < 8; ++j) acc[dy][dx][j] = bias[cog + j];
    for (int ci = 0; ci < 64; ++ci) {
        float v[3][3];
#pragma unroll
        for (int ry = 0; ry < 3; ++ry)
#pragma unroll
            for (int rx = 0; rx < 3; ++rx)
                v[ry][rx] = ls[ci][rb + ry][qx + rx];
#pragma unroll
        for (int j = 0; j < 8; ++j) {
            const float* wp = w + ((cog + j) * 64 + ci) * 16;
            acc[0][0][j] += v[0][0]*wp[0] + v[0][1]*wp[2] + v[1][0]*wp[8]  + v[1][1]*wp[10];
            acc[0][1][j] += v[0][1]*wp[1] + v[0][2]*wp[3] + v[1][1]*wp[9]  + v[1][2]*wp[11];
            acc[1][0][j] += v[1][0]*wp[4] + v[1][1]*wp[6] + v[2][0]*wp[12] + v[2][1]*wp[14];
            acc[1][1][j] += v[1][1]*wp[5] + v[1][2]*wp[7] + v[2][1]*wp[13] + v[2][2]*wp[15];
        }
    }
#pragma unroll
    for (int dy = 0; dy < 2; ++dy)
#pragma unroll
        for (int dx = 0; dx < 2; ++dx)
#pragma unroll
            for (int j = 0; j < 8; ++j)
                out[(size_t)(n * 32 + cog + j) * 4096 + (2*qy+dy) * 64 + 2*qx+dx]
                    = acc[dy][dx][j];
}

// ---- deconv2: BN4+ReLU(d1) staged -> d2 raw. grid(64,64) ----
__global__ void deconv2_k(const float* __restrict__ in, const float* __restrict__ w,
                          const float* __restrict__ bias, const float* __restrict__ g,
                          const float* __restrict__ bt, const double* __restrict__ sum,
                          const double* __restrict__ sq, float* __restrict__ out) {
    __shared__ float ls[32][3][66];
    __shared__ double scd[32], shd[32];
    int b = blockIdx.x, n = blockIdx.y, tid = threadIdx.x;
    bn_consts(tid, 32, sum, sq, g, bt, 1.0 / 262144.0, scd, shd);
    __syncthreads();
    for (int idx = tid; idx < 32 * 3 * 66; idx += 256) {
        int ch = idx / 198, rem = idx - ch * 198, r = rem / 66, cc = rem - r * 66;
        int iy = b - 1 + r, ix = cc - 1;
        float val = 0.f;
        if ((unsigned)iy < 64u && (unsigned)ix < 64u) {
            double v = fma((double)in[(size_t)(n * 32 + ch) * 4096 + iy * 64 + ix],
                           scd[ch], shd[ch]);
            val = v > 0.0 ? (float)v : 0.f;
        }
        ls[ch][r][cc] = val;
    }
    __syncthreads();
    int qx = tid & 63;
    int cog = (tid >> 6) * 4;
    float acc[2][2][4];
#pragma unroll
    for (int dy = 0; dy < 2; ++dy)
#pragma unroll
        for (int dx = 0; dx < 2; ++dx)
#pragma unroll
            for (int j = 0; j < 4; ++j) acc[dy][dx][j] = bias[cog + j];
    for (int ci = 0; ci < 32; ++ci) {
        float v[3][3];
#pragma unroll
        for (int ry = 0; ry < 3; ++ry)
#pragma unroll
            for (int rx = 0; rx < 3; ++rx)
                v[ry][rx] = ls[ci][ry][qx + rx];
#pragma unroll
        for (int j = 0; j < 4; ++j) {
            const float* wp = w + ((cog + j) * 32 + ci) * 16;
            acc[0][0][j] += v[0][0]*wp[0] + v[0][1]*wp[2] + v[1][0]*wp[8]  + v[1][1]*wp[10];
            acc[0][1][j] += v[0][1]*wp[1] + v[0][2]*wp[3] + v[1][1]*wp[9]  + v[1][2]*wp[11];
            acc[1][0][j] += v[1][0]*wp[4] + v[1][1]*wp[6] + v[2][0]*wp[12] + v[2][1]*wp[14];
            acc[1][1][j] += v[1][1]*wp[5] + v[1][2]*wp[7] + v[2][1]*wp[13] + v[2][2]*wp[15];
        }
    }
#pragma unroll
    for (int dy = 0; dy < 2; ++dy)
#pragma unroll
        for (int dx = 0; dx < 2; ++dx)
#pragma unroll
            for (int j = 0; j < 4; ++j)
                out[(size_t)(n * 16 + cog + j) * 16384 + (2*b+dy) * 128 + 2*qx+dx]
                    = acc[dy][dx][j];
}

// ---- deconv3: BN5+ReLU(d2) staged -> d3 raw. grid(64,64) ----
__global__ void deconv3_k(const float* __restrict__ in, const float* __restrict__ w,
                          const float* __restrict__ bias, const float* __restrict__ g,
                          const float* __restrict__ bt, const double* __restrict__ sum,
                          const double* __restrict__ sq, float* __restrict__ out) {
    __shared__ float ls[16][4][130];
    __shared__ double scd[16], shd[16];
    int b = blockIdx.x, n = blockIdx.y, tid = threadIdx.x;
    bn_consts(tid, 16, sum, sq, g, bt, 1.0 / 1048576.0, scd, shd);
    __syncthreads();
    int qy0 = 2 * b;
    for (int idx = tid; idx < 16 * 4 * 130; idx += 256) {
        int ch = idx / 520, rem = idx - ch * 520, r = rem / 130, cc = rem - r * 130;
        int iy = qy0 - 1 + r, ix = cc - 1;
        float val = 0.f;
        if ((unsigned)iy < 128u && (unsigned)ix < 128u) {
            double v = fma((double)in[(size_t)(n * 16 + ch) * 16384 + iy * 128 + ix],
                           scd[ch], shd[ch]);
            val = v > 0.0 ? (float)v : 0.f;
        }
        ls[ch][r][cc] = val;
    }
    __syncthreads();
    int qy = qy0 + (tid >> 7), qx = tid & 127;
    int rb = qy - qy0;
    float acc[2][2][3];
#pragma unroll
    for (int dy = 0; dy < 2; ++dy)
#pragma unroll
        for (int dx = 0; dx < 2; ++dx)
#pragma unroll
            for (int j = 0; j < 3; ++j) acc[dy][dx][j] = bias[j];
    for (int ci = 0; ci < 16; ++ci) {
        float v[3][3];
#pragma unroll
        for (int ry = 0; ry < 3; ++ry)
#pragma unroll
            for (int rx = 0; rx < 3; ++rx)
                v[ry][rx] = ls[ci][rb + ry][qx + rx];
#pragma unroll
        for (int j = 0; j < 3; ++j) {
            const float* wp = w + (j * 16 + ci) * 16;
            acc[0][0][j] += v[0][0]*wp[0] + v[0][1]*wp[2] + v[1][0]*wp[8]  + v[1][1]*wp[10];
            acc[0][1][j] += v[0][1]*wp[1] + v[0][2]*wp[3] + v[1][1]*wp[9]  + v[1][2]*wp[11];
            acc[1][0][j] += v[1][0]*wp[4] + v[1][1]*wp[6] + v[2][0]*wp[12] + v[2][1]*wp[14];
            acc[1][1][j] += v[1][1]*wp[5] + v[1][2]*wp[7] + v[2][1]*wp[13] + v[2][2]*wp[15];
        }
    }
#pragma unroll
    for (int dy = 0; dy < 2; ++dy)
#pragma unroll
        for (int dx = 0; dx < 2; ++dx)
#pragma unroll
            for (int j = 0; j < 3; ++j)
                out[(size_t)(n * 3 + j) * 65536 + (2*qy+dy) * 256 + 2*qx+dx]
                    = acc[dy][dx][j];
}

// ---- final BN + tanh ----
__global__ void bn_tanh_k(const float* __restrict__ y, const double* __restrict__ sum,
                          const double* __restrict__ sq, const float* __restrict__ g,
                          const float* __restrict__ b, float* __restrict__ out, int HW,
                          double invCnt) {
    int hw = blockIdx.x * blockDim.x + threadIdx.x;
    int c = blockIdx.y, n = blockIdx.z, C = gridDim.y;
    double m = sum[c] * invCnt;
    double var = sq[c] * invCnt - m * m;
    double sc = (double)g[c] / sqrt(var + EPS);
    double sh = (double)b[c] - m * sc;
    size_t i = (size_t)(n * C + c) * HW + hw;
    out[i] = (float)tanh(fma((double)y[i], sc, sh));
}

extern "C" void kernel_launch(void* const* d_in, const int* in_sizes, int n_in,
                              void* d_out, int out_size, void* d_ws, size_t ws_size,
                              hipStream_t stream) {
    const float* x   = (const float*)d_in[0];
    const float* cb  = (const float*)d_in[1];
    const float* eW1 = (const float*)d_in[2];
    const float* eb1 = (const float*)d_in[3];
    const float* eg1 = (const float*)d_in[4];
    const float* ebt1= (const float*)d_in[5];
    const float* eW2 = (const float*)d_in[6];
    const float* eb2 = (const float*)d_in[7];
    const float* eg2 = (const float*)d_in[8];
    const float* ebt2= (const float*)d_in[9];
    const float* eW3 = (const float*)d_in[10];
    const float* eb3 = (const float*)d_in[11];
    const float* eg3 = (const float*)d_in[12];
    const float* ebt3= (const float*)d_in[13];
    const float* dW1 = (const float*)d_in[14];
    const float* db1 = (const float*)d_in[15];
    const float* dg1 = (const float*)d_in[16];
    const float* dbt1= (const float*)d_in[17];
    const float* dW2 = (const float*)d_in[18];
    const float* db2 = (const float*)d_in[19];
    const float* dg2 = (const float*)d_in[20];
    const float* dbt2= (const float*)d_in[21];
    const float* dW3 = (const float*)d_in[22];
    const float* db3 = (const float*)d_in[23];
    const float* dg3 = (const float*)d_in[24];
    const float* dbt3= (const float*)d_in[25];

    float* out = (float*)d_out;
    char* ws = (char*)d_ws;
    float* h2    = (float*)ws;                        // [0, 33.5M)
    float* z     = (float*)(ws + 33554432);           // [33.5M, 50.3M)
    float* quant = (float*)(ws + 50331648);           // [50.3M, 67.1M)
    float* d1    = (float*)(ws + 67108864);           // [67.1M, 100.7M)
    float* d2    = (float*)ws;                        // [0, 67.1M)
    float* d3    = (float*)(ws + 67108864);           // [67.1M, 117.4M)
    double* partials = (double*)ws;                   // [0, 128K) dead before h2
    double* stats = (double*)(ws + 117440512);        // 327 doubles
    double* lossAcc = stats + 326;
    float* scc   = (float*)(ws + 117443200);          // 512 f32
    dim3 B(256);

    zero_stats_k<<<2, B, 0, stream>>>(stats, 327);
    scc_k<<<2, B, 0, stream>>>(cb, scc);

    // encoder L1 stats (atomic-free)
    conv1_stats_k<<<dim3(8, 64), B, 0, stream>>>(x, eW1, eb1, partials);
    reduce_stats_k<<<1, 64, 0, stream>>>(partials, stats);
    fused_conv2_k<<<dim3(64, 64), B, 0, stream>>>(x, eW1, eb1, eg1, ebt1, eW2, eb2,
                                                  stats, h2);
    bn_stats_k<<<dim3(32, 64), B, 0, stream>>>(h2, stats + 32, stats + 64, 32, 4096);
    conv3_k<<<dim3(16, 64), B, 0, stream>>>(h2, eW3, eb3, eg2, ebt2,
                                            stats + 32, stats + 64, z);
    bn_stats_k<<<dim3(64, 64), B, 0, stream>>>(z, stats + 96, stats + 160, 64, 1024);
    vq_k<<<256, B, 0, stream>>>(z, cb, scc, eg3, ebt3, stats + 96, stats + 160,
                                quant, lossAcc);
    finalize_loss_k<<<1, 64, 0, stream>>>(lossAcc, out, out_size - 1);

    deconv1_k<<<dim3(16, 64), B, 0, stream>>>(quant, dW1, db1, d1);
    bn_stats_k<<<dim3(32, 64), B, 0, stream>>>(d1, stats + 224, stats + 256, 32, 4096);
    deconv2_k<<<dim3(64, 64), B, 0, stream>>>(d1, dW2, db2, dg1, dbt1,
                                              stats + 224, stats + 256, d2);
    bn_stats_k<<<dim3(16, 64), B, 0, stream>>>(d2, stats + 288, stats + 304, 16, 16384);
    deconv3_k<<<dim3(64, 64), B, 0, stream>>>(d2, dW3, db3, dg2, dbt2,
                                              stats + 288, stats + 304, d3);
    bn_stats_k<<<dim3(3, 64), B, 0, stream>>>(d3, stats + 320, stats + 323, 3, 65536);
    bn_tanh_k<<<dim3(256, 3, 64), B, 0, stream>>>(d3, stats + 320, stats + 323,
                                                  dg3, dbt3, out, 65536,
                                                  1.0 / 4194304.0);
}

// Round 13
// 1782.783 us; speedup vs baseline: 5.7670x; 1.0494x over previous
//
#include <hip/hip_runtime.h>
#include <hip/hip_bf16.h>

// ---------------------------------------------------------------------------
// VQ-VAE forward — R13 (R12 passed @1871us).
//  * Encoder weights pre-converted to f64 once (convert_w_k -> dead d1 ws
//    region): kills ~2000 v_cvt_f64_f32/thread in fused_conv2/conv3/stats
//    (converts were ~= FMA count; VALU-bound at 64.7%).
//  * Per-window x converts hoisted (once per window, not per co).
//  * FMA ORDER BYTE-IDENTICAL to R12 everywhere (f64 reorder-only changes
//    perturb at 1e-16 -> ~1e-9 expected argmin flips; f32 demotion would be
//    ~0.8 flips = R11's failure — NOT done).
// ws: h2@0 | z@33.5M | quant@50.3M | d1@67.1M | d2@0 | d3@67.1M |
//   w64 f64[41728]@67,108,864 (dead until deconv1 overwrites) |
//   partials@0 (dead before h2) | stats f64[327]@117,440,512 | scc@117,443,200
// ---------------------------------------------------------------------------

#define EPS 1e-5

__global__ void zero_stats_k(double* s, int n) {
    int i = blockIdx.x * blockDim.x + threadIdx.x;
    if (i < n) s[i] = 0.0;
}

// convert eW1(768) ++ eW2(8192) ++ eW3(32768) -> f64
__global__ void convert_w_k(const float* __restrict__ w1, const float* __restrict__ w2,
                            const float* __restrict__ w3, double* __restrict__ w64) {
    int i = blockIdx.x * blockDim.x + threadIdx.x;
    if (i < 768) w64[i] = (double)w1[i];
    else if (i < 768 + 8192) w64[i] = (double)w2[i - 768];
    else if (i < 768 + 8192 + 32768) w64[i] = (double)w3[i - 768 - 8192];
}

__device__ __forceinline__ void block_reduce2(double v1, double v2,
                                              double* t1, double* t2) {
#pragma unroll
    for (int o = 32; o; o >>= 1) {
        v1 += __shfl_down(v1, o);
        v2 += __shfl_down(v2, o);
    }
    __shared__ double ls[4][2];
    int wid = threadIdx.x >> 6, lane = threadIdx.x & 63;
    if (lane == 0) { ls[wid][0] = v1; ls[wid][1] = v2; }
    __syncthreads();
    if (threadIdx.x == 0) {
        atomicAdd(t1, ls[0][0] + ls[1][0] + ls[2][0] + ls[3][0]);
        atomicAdd(t2, ls[0][1] + ls[1][1] + ls[2][1] + ls[3][1]);
    }
    __syncthreads();
}

// ---- conv1 stats: atomic-free, f64 weights. grid(8,64) ----
__global__ void conv1_stats_k(const float* __restrict__ x, const double* __restrict__ w64,
                              const float* __restrict__ bias,
                              double* __restrict__ partials) {
    __shared__ float xs[3][6][258];
    __shared__ double lsw[4][32];
    int band = blockIdx.x, n = blockIdx.y, tid = threadIdx.x;
    double sums[16], sqs[16];
#pragma unroll
    for (int j = 0; j < 16; ++j) { sums[j] = 0.0; sqs[j] = 0.0; }
    for (int s8 = 0; s8 < 8; ++s8) {
        int strip = band * 8 + s8;
        int iyBase = 4 * strip - 1;
        __syncthreads();
        for (int idx = tid; idx < 3 * 6 * 258; idx += 256) {
            int ch = idx / 1548, rem = idx - ch * 1548, r = rem / 258, cc = rem - r * 258;
            int iy = iyBase + r, ix = cc - 1;
            float v = 0.f;
            if ((unsigned)iy < 256u && (unsigned)ix < 256u)
                v = x[(size_t)(n * 3 + ch) * 65536 + iy * 256 + ix];
            xs[ch][r][cc] = v;
        }
        __syncthreads();
        int lr = 2 * (tid >> 7), lc = 2 * (tid & 127);
        double xd[3][4][4];
#pragma unroll
        for (int ci = 0; ci < 3; ++ci)
#pragma unroll
            for (int ky = 0; ky < 4; ++ky)
#pragma unroll
                for (int kx = 0; kx < 4; ++kx)
                    xd[ci][ky][kx] = (double)xs[ci][lr + ky][lc + kx];
#pragma unroll
        for (int co = 0; co < 16; ++co) {
            double acc = (double)bias[co];
            const double* wp = w64 + co * 48;
#pragma unroll
            for (int ci = 0; ci < 3; ++ci)
#pragma unroll
                for (int ky = 0; ky < 4; ++ky)
#pragma unroll
                    for (int kx = 0; kx < 4; ++kx)
                        acc = fma(xd[ci][ky][kx], wp[ci * 16 + ky * 4 + kx], acc);
            sums[co] += acc;
            sqs[co] = fma(acc, acc, sqs[co]);
        }
    }
    double val[32];
#pragma unroll
    for (int j = 0; j < 16; ++j) { val[j] = sums[j]; val[16 + j] = sqs[j]; }
#pragma unroll
    for (int o = 32; o; o >>= 1)
#pragma unroll
        for (int j = 0; j < 32; ++j) val[j] += __shfl_down(val[j], o);
    int wid = tid >> 6, lane = tid & 63;
    if (lane == 0)
#pragma unroll
        for (int j = 0; j < 32; ++j) lsw[wid][j] = val[j];
    __syncthreads();
    if (tid < 32) {
        double p = lsw[0][tid] + lsw[1][tid] + lsw[2][tid] + lsw[3][tid];
        partials[(size_t)(n * 8 + band) * 32 + tid] = p;
    }
}

__global__ void reduce_stats_k(const double* __restrict__ partials,
                               double* __restrict__ stats) {
    int t = threadIdx.x;
    if (t < 32) {
        double s = 0.0;
        for (int i = 0; i < 512; ++i) s += partials[(size_t)i * 32 + t];
        stats[t] = s;
    }
}

// ---- fused conv1+BN1+ReLU -> conv2 -> h2 (f64 weights). grid(64,64) ----
__global__ void fused_conv2_k(const float* __restrict__ x, const double* __restrict__ w1_64,
                              const float* __restrict__ eb1, const float* __restrict__ eg1,
                              const float* __restrict__ ebt1, const double* __restrict__ w2_64,
                              const float* __restrict__ eb2, const double* __restrict__ stats,
                              float* __restrict__ h2) {
    __shared__ float xs[3][38][38];
    __shared__ float h1s[16][18][18];
    int tile = blockIdx.x, n = blockIdx.y, tid = threadIdx.x;
    int ty = tile >> 3, tx = tile & 7;
    int iyBase = 32 * ty - 3, ixBase = 32 * tx - 3;
    for (int idx = tid; idx < 3 * 38 * 38; idx += 256) {
        int ch = idx / 1444, rem = idx - ch * 1444, r = rem / 38, cc = rem - r * 38;
        int iy = iyBase + r, ix = ixBase + cc;
        float v = 0.f;
        if ((unsigned)iy < 256u && (unsigned)ix < 256u)
            v = x[(size_t)(n * 3 + ch) * 65536 + iy * 256 + ix];
        xs[ch][r][cc] = v;
    }
    __syncthreads();
    int hy0 = 16 * ty - 1, hx0 = 16 * tx - 1;
    for (int idx = tid; idx < 16 * 18 * 18; idx += 256) {
        int ci = idx / 324, rem = idx - ci * 324, r = rem / 18, cc = rem - r * 18;
        int hy = hy0 + r, hx = hx0 + cc;
        float val = 0.f;
        if ((unsigned)hy < 128u && (unsigned)hx < 128u) {
            double xd[3][4][4];
#pragma unroll
            for (int c3 = 0; c3 < 3; ++c3)
#pragma unroll
                for (int ky = 0; ky < 4; ++ky)
#pragma unroll
                    for (int kx = 0; kx < 4; ++kx)
                        xd[c3][ky][kx] = (double)xs[c3][2 * r + ky][2 * cc + kx];
            double acc = (double)eb1[ci];
            const double* wp = w1_64 + ci * 48;
#pragma unroll
            for (int c3 = 0; c3 < 3; ++c3)
#pragma unroll
                for (int ky = 0; ky < 4; ++ky)
#pragma unroll
                    for (int kx = 0; kx < 4; ++kx)
                        acc = fma(xd[c3][ky][kx], wp[c3 * 16 + ky * 4 + kx], acc);
            double m = stats[ci] * (1.0 / 1048576.0);
            double var = stats[16 + ci] * (1.0 / 1048576.0) - m * m;
            double sc = (double)eg1[ci] / sqrt(var + EPS);
            double sh = (double)ebt1[ci] - m * sc;
            double v = fma(acc, sc, sh);
            val = (float)(v > 0.0 ? v : 0.0);
        }
        h1s[ci][r][cc] = val;
    }
    __syncthreads();
    int s = tid & 63, ly = s >> 3, lx = s & 7;
    int cog = __builtin_amdgcn_readfirstlane((tid >> 6) * 8);
    double acc[8];
#pragma unroll
    for (int j = 0; j < 8; ++j) acc[j] = (double)eb2[cog + j];
    for (int ci = 0; ci < 16; ++ci) {
        double td[16];
#pragma unroll
        for (int ky = 0; ky < 4; ++ky)
#pragma unroll
            for (int kx = 0; kx < 4; ++kx)
                td[ky * 4 + kx] = (double)h1s[ci][2 * ly + ky][2 * lx + kx];
#pragma unroll
        for (int j = 0; j < 8; ++j) {
            const double* wp = w2_64 + ((cog + j) * 16 + ci) * 16;
#pragma unroll
            for (int k = 0; k < 16; ++k)
                acc[j] = fma(td[k], wp[k], acc[j]);
        }
    }
    int oy = 8 * ty + ly, ox = 8 * tx + lx;
#pragma unroll
    for (int j = 0; j < 8; ++j)
        h2[(size_t)(n * 32 + cog + j) * 4096 + oy * 64 + ox] = (float)acc[j];
}

// ---- generic BN stats ----
__global__ void bn_stats_k(const float* __restrict__ y, double* __restrict__ sum,
                           double* __restrict__ sq, int C, int HW) {
    int c = blockIdx.x, n = blockIdx.y;
    const float* p = y + (size_t)(n * C + c) * HW;
    double s = 0.0, s2 = 0.0;
    for (int i = threadIdx.x; i < HW; i += blockDim.x) {
        double v = (double)p[i];
        s += v;
        s2 = fma(v, v, s2);
    }
    block_reduce2(s, s2, &sum[c], &sq[c]);
}

__device__ __forceinline__ void bn_consts(int tid, int C, const double* sum,
                                          const double* sq, const float* g,
                                          const float* b, double invCnt,
                                          double* scd, double* shd) {
    if (tid < C) {
        double m = sum[tid] * invCnt;
        double var = sq[tid] * invCnt - m * m;
        double sc = (double)g[tid] / sqrt(var + EPS);
        scd[tid] = sc;
        shd[tid] = (double)b[tid] - m * sc;
    }
}

// ---- conv3: BN2+ReLU(h2) staged -> z raw f32 (f64 weights). grid(16,64) ----
__global__ void conv3_k(const float* __restrict__ h2, const double* __restrict__ w3_64,
                        const float* __restrict__ bias, const float* __restrict__ eg2,
                        const float* __restrict__ ebt2, const double* __restrict__ sum2,
                        const double* __restrict__ sq2, float* __restrict__ z3) {
    __shared__ float hs[32][6][66];
    __shared__ double scd[32], shd[32];
    int c = blockIdx.x, n = blockIdx.y, tid = threadIdx.x;
    bn_consts(tid, 32, sum2, sq2, eg2, ebt2, 1.0 / 262144.0, scd, shd);
    __syncthreads();
    int iyBase = 4 * c - 1;
    for (int idx = tid; idx < 32 * 6 * 66; idx += 256) {
        int ch = idx / 396, rem = idx - ch * 396, r = rem / 66, cc = rem - r * 66;
        int iy = iyBase + r, ix = cc - 1;
        float val = 0.f;
        if ((unsigned)iy < 64u && (unsigned)ix < 64u) {
            double v = fma((double)h2[(size_t)(n * 32 + ch) * 4096 + iy * 64 + ix],
                           scd[ch], shd[ch]);
            val = v > 0.0 ? (float)v : 0.f;
        }
        hs[ch][r][cc] = val;
    }
    __syncthreads();
    int s = tid & 63;
    int oy = 2 * c + (s >> 5), ox = s & 31;
    int lr = 2 * (s >> 5), lc = 2 * ox;
    int cog = __builtin_amdgcn_readfirstlane((tid >> 6) * 16);
    double acc[16];
#pragma unroll
    for (int j = 0; j < 16; ++j) acc[j] = (double)bias[cog + j];
    for (int ci = 0; ci < 32; ++ci) {
        double td[16];
#pragma unroll
        for (int ky = 0; ky < 4; ++ky)
#pragma unroll
            for (int kx = 0; kx < 4; ++kx)
                td[ky * 4 + kx] = (double)hs[ci][lr + ky][lc + kx];
#pragma unroll
        for (int j = 0; j < 16; ++j) {
            const double* wp = w3_64 + ((cog + j) * 32 + ci) * 16;
#pragma unroll
            for (int k = 0; k < 16; ++k)
                acc[j] = fma(td[k], wp[k], acc[j]);
        }
    }
#pragma unroll
    for (int j = 0; j < 16; ++j)
        z3[(size_t)(n * 64 + cog + j) * 1024 + oy * 32 + ox] = (float)acc[j];
}

__device__ __forceinline__ float np_sum64(const float* a) {
    float r[8];
#pragma unroll
    for (int j = 0; j < 8; ++j) r[j] = a[j];
#pragma unroll
    for (int m = 1; m < 8; ++m)
#pragma unroll
        for (int j = 0; j < 8; ++j) r[j] += a[m * 8 + j];
    return ((r[0] + r[1]) + (r[2] + r[3])) + ((r[4] + r[5]) + (r[6] + r[7]));
}

__global__ void scc_k(const float* __restrict__ cb, float* __restrict__ scc) {
    int k = blockIdx.x * blockDim.x + threadIdx.x;
    if (k >= 512) return;
    const float* c = cb + (k << 6);
    float cc[64];
#pragma unroll
    for (int d = 0; d < 64; ++d) cc[d] = c[d] * c[d];
    scc[k] = np_sum64(cc);
}

// ---- VQ: BN3+ReLU in-register; np-mimic f32 argmin; f64 loss ----
__global__ void vq_k(const float* __restrict__ zraw, const float* __restrict__ cb,
                     const float* __restrict__ scc, const float* __restrict__ eg3,
                     const float* __restrict__ ebt3, const double* __restrict__ sum3,
                     const double* __restrict__ sq3, float* __restrict__ quant,
                     double* __restrict__ lossAcc) {
    __shared__ double scd[64], shd[64];
    bn_consts(threadIdx.x, 64, sum3, sq3, eg3, ebt3, 1.0 / 65536.0, scd, shd);
    __syncthreads();
    int p = blockIdx.x * blockDim.x + threadIdx.x;
    int n = p >> 10, hw = p & 1023;
    const float* zp = zraw + (size_t)n * 65536 + hw;
    float z32[64], zz[64];
#pragma unroll
    for (int d = 0; d < 64; ++d) {
        double v = fma((double)zp[d * 1024], scd[d], shd[d]);
        z32[d] = v > 0.0 ? (float)v : 0.f;
        zz[d] = z32[d] * z32[d];
    }
    float sz = np_sum64(zz);
    float bestf = 3.4e38f;
    int bif = 0;
    for (int k = 0; k < 512; ++k) {
        const float* c = cb + (k << 6);
        float dot = 0.f;
#pragma unroll
        for (int d = 0; d < 64; ++d) dot = fmaf(z32[d], c[d], dot);
        float distf = (sz + scc[k]) - 2.f * dot;
        if (distf < bestf) { bestf = distf; bif = k; }
    }
    const float* c = cb + (bif << 6);
    float* qp = quant + (size_t)n * 65536 + hw;
    double dist = 0.0;
#pragma unroll
    for (int d = 0; d < 64; ++d) {
        double diff = (double)z32[d] - (double)c[d];
        dist = fma(diff, diff, dist);
        qp[d * 1024] = c[d];
    }
    double s = dist;
#pragma unroll
    for (int o = 32; o; o >>= 1) s += __shfl_down(s, o);
    if ((threadIdx.x & 63) == 0) atomicAdd(lossAcc, s);
}

__global__ void finalize_loss_k(const double* lossAcc, float* out, int idx) {
    if (threadIdx.x == 0 && blockIdx.x == 0)
        out[idx] = (float)(2.0 * (*lossAcc) / 4194304.0);
}

// ---- deconv1 ----
__global__ void deconv1_k(const float* __restrict__ in, const float* __restrict__ w,
                          const float* __restrict__ bias, float* __restrict__ out) {
    __shared__ float ls[64][4][34];
    int b = blockIdx.x, n = blockIdx.y, tid = threadIdx.x;
    int qy0 = 2 * b;
    for (int idx = tid; idx < 64 * 4 * 34; idx += 256) {
        int ch = idx / 136, rem = idx - ch * 136, r = rem / 34, cc = rem - r * 34;
        int iy = qy0 - 1 + r, ix = cc - 1;
        float v = 0.f;
        if ((unsigned)iy < 32u && (unsigned)ix < 32u)
            v = in[(size_t)(n * 64 + ch) * 1024 + iy * 32 + ix];
        ls[ch][r][cc] = v;
    }
    __syncthreads();
    int pt = tid & 63;
    int qy = qy0 + (pt >> 5), qx = pt & 31;
    int cog = (tid >> 6) * 8;
    int rb = qy - qy0;
    float acc[2][2][8];
#pragma unroll
    for (int dy = 0; dy < 2; ++dy)
#pragma unroll
        for (int dx = 0; dx < 2; ++dx)
#pragma unroll
            for (int j = 0; j < 8; ++j) acc[dy][dx][j] = bias[cog + j];
    for (int ci = 0; ci < 64; ++ci) {
        float v[3][3];
#pragma unroll
        for (int ry = 0; ry < 3; ++ry)
#pragma unroll
            for (int rx = 0; rx < 3; ++rx)
                v[ry][rx] = ls[ci][rb + ry][qx + rx];
#pragma unroll
        for (int j = 0; j < 8; ++j) {
            const float* wp = w + ((cog + j) * 64 + ci) * 16;
            acc[0][0][j] += v[0][0]*wp[0] + v[0][1]*wp[2] + v[1][0]*wp[8]  + v[1][1]*wp[10];
            acc[0][1][j] += v[0][1]*wp[1] + v[0][2]*wp[3] + v[1][1]*wp[9]  + v[1][2]*wp[11];
            acc[1][0][j] += v[1][0]*wp[4] + v[1][1]*wp[6] + v[2][0]*wp[12] + v[2][1]*wp[14];
            acc[1][1][j] += v[1][1]*wp[5] + v[1][2]*wp[7] + v[2][1]*wp[13] + v[2][2]*wp[15];
        }
    }
#pragma unroll
    for (int dy = 0; dy < 2; ++dy)
#pragma unroll
        for (int dx = 0; dx < 2; ++dx)
#pragma unroll
            for (int j = 0; j < 8; ++j)
                out[(size_t)(n * 32 + cog + j) * 4096 + (2*qy+dy) * 64 + 2*qx+dx]
                    = acc[dy][dx][j];
}

// ---- deconv2: BN4+ReLU(d1) staged ----
__global__ void deconv2_k(const float* __restrict__ in, const float* __restrict__ w,
                          const float* __restrict__ bias, const float* __restrict__ g,
                          const float* __restrict__ bt, const double* __restrict__ sum,
                          const double* __restrict__ sq, float* __restrict__ out) {
    __shared__ float ls[32][3][66];
    __shared__ double scd[32], shd[32];
    int b = blockIdx.x, n = blockIdx.y, tid = threadIdx.x;
    bn_consts(tid, 32, sum, sq, g, bt, 1.0 / 262144.0, scd, shd);
    __syncthreads();
    for (int idx = tid; idx < 32 * 3 * 66; idx += 256) {
        int ch = idx / 198, rem = idx - ch * 198, r = rem / 66, cc = rem - r * 66;
        int iy = b - 1 + r, ix = cc - 1;
        float val = 0.f;
        if ((unsigned)iy < 64u && (unsigned)ix < 64u) {
            double v = fma((double)in[(size_t)(n * 32 + ch) * 4096 + iy * 64 + ix],
                           scd[ch], shd[ch]);
            val = v > 0.0 ? (float)v : 0.f;
        }
        ls[ch][r][cc] = val;
    }
    __syncthreads();
    int qx = tid & 63;
    int cog = (tid >> 6) * 4;
    float acc[2][2][4];
#pragma unroll
    for (int dy = 0; dy < 2; ++dy)
#pragma unroll
        for (int dx = 0; dx < 2; ++dx)
#pragma unroll
            for (int j = 0; j < 4; ++j) acc[dy][dx][j] = bias[cog + j];
    for (int ci = 0; ci < 32; ++ci) {
        float v[3][3];
#pragma unroll
        for (int ry = 0; ry < 3; ++ry)
#pragma unroll
            for (int rx = 0; rx < 3; ++rx)
                v[ry][rx] = ls[ci][ry][qx + rx];
#pragma unroll
        for (int j = 0; j < 4; ++j) {
            const float* wp = w + ((cog + j) * 32 + ci) * 16;
            acc[0][0][j] += v[0][0]*wp[0] + v[0][1]*wp[2] + v[1][0]*wp[8]  + v[1][1]*wp[10];
            acc[0][1][j] += v[0][1]*wp[1] + v[0][2]*wp[3] + v[1][1]*wp[9]  + v[1][2]*wp[11];
            acc[1][0][j] += v[1][0]*wp[4] + v[1][1]*wp[6] + v[2][0]*wp[12] + v[2][1]*wp[14];
            acc[1][1][j] += v[1][1]*wp[5] + v[1][2]*wp[7] + v[2][1]*wp[13] + v[2][2]*wp[15];
        }
    }
#pragma unroll
    for (int dy = 0; dy < 2; ++dy)
#pragma unroll
        for (int dx = 0; dx < 2; ++dx)
#pragma unroll
            for (int j = 0; j < 4; ++j)
                out[(size_t)(n * 16 + cog + j) * 16384 + (2*b+dy) * 128 + 2*qx+dx]
                    = acc[dy][dx][j];
}

// ---- deconv3: BN5+ReLU(d2) staged ----
__global__ void deconv3_k(const float* __restrict__ in, const float* __restrict__ w,
                          const float* __restrict__ bias, const float* __restrict__ g,
                          const float* __restrict__ bt, const double* __restrict__ sum,
                          const double* __restrict__ sq, float* __restrict__ out) {
    __shared__ float ls[16][4][130];
    __shared__ double scd[16], shd[16];
    int b = blockIdx.x, n = blockIdx.y, tid = threadIdx.x;
    bn_consts(tid, 16, sum, sq, g, bt, 1.0 / 1048576.0, scd, shd);
    __syncthreads();
    int qy0 = 2 * b;
    for (int idx = tid; idx < 16 * 4 * 130; idx += 256) {
        int ch = idx / 520, rem = idx - ch * 520, r = rem / 130, cc = rem - r * 130;
        int iy = qy0 - 1 + r, ix = cc - 1;
        float val = 0.f;
        if ((unsigned)iy < 128u && (unsigned)ix < 128u) {
            double v = fma((double)in[(size_t)(n * 16 + ch) * 16384 + iy * 128 + ix],
                           scd[ch], shd[ch]);
            val = v > 0.0 ? (float)v : 0.f;
        }
        ls[ch][r][cc] = val;
    }
    __syncthreads();
    int qy = qy0 + (tid >> 7), qx = tid & 127;
    int rb = qy - qy0;
    float acc[2][2][3];
#pragma unroll
    for (int dy = 0; dy < 2; ++dy)
#pragma unroll
        for (int dx = 0; dx < 2; ++dx)
#pragma unroll
            for (int j = 0; j < 3; ++j) acc[dy][dx][j] = bias[j];
    for (int ci = 0; ci < 16; ++ci) {
        float v[3][3];
#pragma unroll
        for (int ry = 0; ry < 3; ++ry)
#pragma unroll
            for (int rx = 0; rx < 3; ++rx)
                v[ry][rx] = ls[ci][rb + ry][qx + rx];
#pragma unroll
        for (int j = 0; j < 3; ++j) {
            const float* wp = w + (j * 16 + ci) * 16;
            acc[0][0][j] += v[0][0]*wp[0] + v[0][1]*wp[2] + v[1][0]*wp[8]  + v[1][1]*wp[10];
            acc[0][1][j] += v[0][1]*wp[1] + v[0][2]*wp[3] + v[1][1]*wp[9]  + v[1][2]*wp[11];
            acc[1][0][j] += v[1][0]*wp[4] + v[1][1]*wp[6] + v[2][0]*wp[12] + v[2][1]*wp[14];
            acc[1][1][j] += v[1][1]*wp[5] + v[1][2]*wp[7] + v[2][1]*wp[13] + v[2][2]*wp[15];
        }
    }
#pragma unroll
    for (int dy = 0; dy < 2; ++dy)
#pragma unroll
        for (int dx = 0; dx < 2; ++dx)
#pragma unroll
            for (int j = 0; j < 3; ++j)
                out[(size_t)(n * 3 + j) * 65536 + (2*qy+dy) * 256 + 2*qx+dx]
                    = acc[dy][dx][j];
}

// ---- final BN + tanh ----
__global__ void bn_tanh_k(const float* __restrict__ y, const double* __restrict__ sum,
                          const double* __restrict__ sq, const float* __restrict__ g,
                          const float* __restrict__ b, float* __restrict__ out, int HW,
                          double invCnt) {
    int hw = blockIdx.x * blockDim.x + threadIdx.x;
    int c = blockIdx.y, n = blockIdx.z, C = gridDim.y;
    double m = sum[c] * invCnt;
    double var = sq[c] * invCnt - m * m;
    double sc = (double)g[c] / sqrt(var + EPS);
    double sh = (double)b[c] - m * sc;
    size_t i = (size_t)(n * C + c) * HW + hw;
    out[i] = (float)tanh(fma((double)y[i], sc, sh));
}

extern "C" void kernel_launch(void* const* d_in, const int* in_sizes, int n_in,
                              void* d_out, int out_size, void* d_ws, size_t ws_size,
                              hipStream_t stream) {
    const float* x   = (const float*)d_in[0];
    const float* cb  = (const float*)d_in[1];
    const float* eW1 = (const float*)d_in[2];
    const float* eb1 = (const float*)d_in[3];
    const float* eg1 = (const float*)d_in[4];
    const float* ebt1= (const float*)d_in[5];
    const float* eW2 = (const float*)d_in[6];
    const float* eb2 = (const float*)d_in[7];
    const float* eg2 = (const float*)d_in[8];
    const float* ebt2= (const float*)d_in[9];
    const float* eW3 = (const float*)d_in[10];
    const float* eb3 = (const float*)d_in[11];
    const float* eg3 = (const float*)d_in[12];
    const float* ebt3= (const float*)d_in[13];
    const float* dW1 = (const float*)d_in[14];
    const float* db1 = (const float*)d_in[15];
    const float* dg1 = (const float*)d_in[16];
    const float* dbt1= (const float*)d_in[17];
    const float* dW2 = (const float*)d_in[18];
    const float* db2 = (const float*)d_in[19];
    const float* dg2 = (const float*)d_in[20];
    const float* dbt2= (const float*)d_in[21];
    const float* dW3 = (const float*)d_in[22];
    const float* db3 = (const float*)d_in[23];
    const float* dg3 = (const float*)d_in[24];
    const float* dbt3= (const float*)d_in[25];

    float* out = (float*)d_out;
    char* ws = (char*)d_ws;
    float* h2    = (float*)ws;                        // [0, 33.5M)
    float* z     = (float*)(ws + 33554432);           // [33.5M, 50.3M)
    float* quant = (float*)(ws + 50331648);           // [50.3M, 67.1M)
    float* d1    = (float*)(ws + 67108864);           // [67.1M, 100.7M)
    float* d2    = (float*)ws;                        // [0, 67.1M)
    float* d3    = (float*)(ws + 67108864);           // [67.1M, 117.4M)
    double* partials = (double*)ws;                   // [0, 128K) dead before h2
    double* w64  = (double*)(ws + 67108864);          // 41728 f64, dead before d1
    double* w1_64 = w64;
    double* w2_64 = w64 + 768;
    double* w3_64 = w64 + 768 + 8192;
    double* stats = (double*)(ws + 117440512);        // 327 doubles
    double* lossAcc = stats + 326;
    float* scc   = (float*)(ws + 117443200);          // 512 f32
    dim3 B(256);

    zero_stats_k<<<2, B, 0, stream>>>(stats, 327);
    scc_k<<<2, B, 0, stream>>>(cb, scc);
    convert_w_k<<<163, B, 0, stream>>>(eW1, eW2, eW3, w64);

    // encoder
    conv1_stats_k<<<dim3(8, 64), B, 0, stream>>>(x, w1_64, eb1, partials);
    reduce_stats_k<<<1, 64, 0, stream>>>(partials, stats);
    fused_conv2_k<<<dim3(64, 64), B, 0, stream>>>(x, w1_64, eb1, eg1, ebt1, w2_64,
                                                  eb2, stats, h2);
    bn_stats_k<<<dim3(32, 64), B, 0, stream>>>(h2, stats + 32, stats + 64, 32, 4096);
    conv3_k<<<dim3(16, 64), B, 0, stream>>>(h2, w3_64, eb3, eg2, ebt2,
                                            stats + 32, stats + 64, z);
    bn_stats_k<<<dim3(64, 64), B, 0, stream>>>(z, stats + 96, stats + 160, 64, 1024);
    vq_k<<<256, B, 0, stream>>>(z, cb, scc, eg3, ebt3, stats + 96, stats + 160,
                                quant, lossAcc);
    finalize_loss_k<<<1, 64, 0, stream>>>(lossAcc, out, out_size - 1);

    // decoder
    deconv1_k<<<dim3(16, 64), B, 0, stream>>>(quant, dW1, db1, d1);
    bn_stats_k<<<dim3(32, 64), B, 0, stream>>>(d1, stats + 224, stats + 256, 32, 4096);
    deconv2_k<<<dim3(64, 64), B, 0, stream>>>(d1, dW2, db2, dg1, dbt1,
                                              stats + 224, stats + 256, d2);
    bn_stats_k<<<dim3(16, 64), B, 0, stream>>>(d2, stats + 288, stats + 304, 16, 16384);
    deconv3_k<<<dim3(64, 64), B, 0, stream>>>(d2, dW3, db3, dg2, dbt2,
                                              stats + 288, stats + 304, d3);
    bn_stats_k<<<dim3(3, 64), B, 0, stream>>>(d3, stats + 320, stats + 323, 3, 65536);
    bn_tanh_k<<<dim3(256, 3, 64), B, 0, stream>>>(d3, stats + 320, stats + 323,
                                                  dg3, dbt3, out, 65536,
                                                  1.0 / 4194304.0);
}